// Round 4
// baseline (602.920 us; speedup 1.0000x reference)
//
#include <hip/hip_runtime.h>
#include <hip/hip_bf16.h>
#include <math.h>

// Problem constants
#define B_SZ   1024
#define D_SZ   512
#define KC_SZ  256
#define NLOW   130816            // 512*511/2

// B pages: per class, 20 K-step pages of 16 KB, stored in per-wave MFMA
// fragment order: line = ((wng*4+ni)*2+h)*64 + lane, lane = q*16+c,
// value[j] = L[d][e], e = wng*64+ni*16+c, d_local = h*32+q*8+j.
#define STEP_ELEMS  8192
#define NSTEPS      20           // 8+6+4+2 triangular K-steps
#define CLASS_ELEMS (NSTEPS * STEP_ELEMS)   // 320 KB/class

// Workspace layout (bytes)
#define OFF_XP     (size_t)(KC_SZ * CLASS_ELEMS * 2)        // 83886080
#define OFF_TPART  (OFF_XP + 64 * STEP_ELEMS * 2)           // +1 MiB
#define OFF_T      (OFF_TPART + (size_t)KC_SZ * 8 * 512 * 4)// +4 MiB
#define WS_NEED    (OFF_T + (size_t)KC_SZ * 512 * 4)        // ~85.5 MiB

typedef __attribute__((ext_vector_type(4))) float  f32x4;
typedef __attribute__((ext_vector_type(4), aligned(4))) float f32x4u; // align-4 vector load
typedef __attribute__((ext_vector_type(8))) __bf16 bf16x8;

// steps before col-tile ct
__device__ __forceinline__ int sbase_of(int ct) { return ct * (9 - ct); }
// s -> dt (also the A-page k-chunk)
__device__ __forceinline__ int kch_of(int s) {
    return (s < 8) ? s : (s < 14) ? s - 6 : (s < 18) ? s - 10 : s - 12;
}

// ---------------------------------------------------------------------------
// K1a: X pages, bf16, A-fragment order. 256 blocks (pg 0..63 x quarter 0..3).
// ---------------------------------------------------------------------------
__global__ __launch_bounds__(256)
void prep_x(const float* __restrict__ X, __hip_bfloat16* __restrict__ Xp) {
    const int bx  = blockIdx.x;
    const int pg  = bx >> 2;             // mt*8 + kch
    const int mt  = pg >> 3, kch = pg & 7;
    __bf16* out = (__bf16*)Xp + (size_t)pg * STEP_ELEMS;
    const int line = threadIdx.x + (bx & 3) * 256;   // 0..1023
    const int wmg = line >> 9, mi = (line >> 7) & 3, h = (line >> 6) & 1;
    const int lane = line & 63, q = lane >> 4, c = lane & 15;
    const int row = mt * 128 + wmg * 64 + mi * 16 + c;
    const float* src = X + (size_t)row * D_SZ + kch * 64 + h * 32 + q * 8;
    f32x4 v0 = ((const f32x4*)src)[0];
    f32x4 v1 = ((const f32x4*)src)[1];
    bf16x8 p;
    #pragma unroll
    for (int j = 0; j < 4; ++j) { p[j] = (__bf16)v0[j]; p[j + 4] = (__bf16)v1[j]; }
    *(bf16x8*)(out + line * 8) = p;
}

// ---------------------------------------------------------------------------
// K1b: one block per (class, page). Vector f32x4 global reads, bf16
// transposed LDS tile [e][d] with XOR-swizzled 16B blocks so the fragment
// read is a single conflict-free ds_read_b128. t-partials from the f32
// registers (fp32 exact), tpart layout unchanged.
// ---------------------------------------------------------------------------
__global__ __launch_bounds__(256)
void prep_b(const float* __restrict__ Ldiag,
            const float* __restrict__ Llow,
            const float* __restrict__ W,
            __hip_bfloat16* __restrict__ Bp,
            float* __restrict__ tpart) {
    __shared__ __bf16 Lt[128 * 64];      // [e_local][d_local], 16B-block XOR swizzle
    __shared__ float  ptl[32 * 129];     // [m][e_local], padded: bank=(m+e)%32

    const int s  = blockIdx.x;           // page 0..19
    const int kc = blockIdx.y;           // class
    const int ct = (s < 8) ? 0 : (s < 14) ? 1 : (s < 18) ? 2 : 3;
    const int dt = kch_of(s);
    const int e0 = ct << 7, d0 = dt << 6;

    const int tid = threadIdx.x;
    const int m   = tid & 31;            // d row-pair index
    const int seg = tid >> 5;            // e 16-chunk index
    const int es  = seg << 4;            // e_local chunk start
    const int dg0 = d0 + 2 * m;          // global d of row 0 (row 1 = dg0+1)

    // classify this thread's 16-e chunk:
    // 0 = pure strict-lower (vector loads), 1 = straddles diagonal, 2 = zero
    int cls;
    if (dt >= 2 * ct + 2)      cls = 0;
    else if (dt == 2 * ct + 1) cls = (seg < 4) ? 0 : 1;
    else                       cls = (seg < 4) ? 1 : 2;

    const float* lowb = Llow + (size_t)kc * NLOW;
    const float2 wv = *(const float2*)(W + (size_t)kc * D_SZ + dg0);

    float v0[16], v1[16];
    if (cls == 0) {
        const int t0 = (dg0 * (dg0 - 1)) >> 1;       // tri(dg0)
        const int t1 = t0 + dg0;                     // tri(dg0+1)
        const float* s0 = lowb + t0 + e0 + es;
        const float* s1 = lowb + t1 + e0 + es;
        #pragma unroll
        for (int i = 0; i < 4; ++i) {
            f32x4u a = ((const f32x4u*)s0)[i];
            f32x4u b = ((const f32x4u*)s1)[i];
            #pragma unroll
            for (int j = 0; j < 4; ++j) { v0[i * 4 + j] = a[j]; v1[i * 4 + j] = b[j]; }
        }
    } else if (cls == 1) {
        const int t0 = (dg0 * (dg0 - 1)) >> 1;
        const int t1 = t0 + dg0;
        const float* diagb = Ldiag + (size_t)kc * D_SZ;
        float q0 = diagb[dg0],     q1 = diagb[dg0 + 1];
        q0 *= q0; q1 *= q1;
        #pragma unroll
        for (int j = 0; j < 16; ++j) {
            const int eg = e0 + es + j;
            v0[j] = (eg < dg0)     ? lowb[t0 + eg] : ((eg == dg0)     ? q0 : 0.f);
            v1[j] = (eg < dg0 + 1) ? lowb[t1 + eg] : ((eg == dg0 + 1) ? q1 : 0.f);
        }
    } else {
        #pragma unroll
        for (int j = 0; j < 16; ++j) { v0[j] = 0.f; v1[j] = 0.f; }
    }

    // transposed bf16 pair writes (conflict-free) + fp32 t-partials
    char* ltb = (char*)Lt;
    #pragma unroll
    for (int j = 0; j < 16; ++j) {
        const int el = es + j;
        union { __bf16 h[2]; unsigned u; } pk;
        pk.h[0] = (__bf16)v0[j];
        pk.h[1] = (__bf16)v1[j];
        const int off = el * 128 + ((4 * m) ^ ((el & 7) << 4));
        *(unsigned*)(ltb + off) = pk.u;
        ptl[m * 129 + el] = wv.x * v0[j] + wv.y * v1[j];
    }
    __syncthreads();

    // fragment-order page out: 4 lines/thread, one ds_read_b128 + 16B store each
    __bf16* page = (__bf16*)Bp + (size_t)kc * CLASS_ELEMS + (size_t)s * STEP_ELEMS;
    const int lane = tid & 63, q = lane >> 4, c = lane & 15;
    #pragma unroll
    for (int k = 0; k < 4; ++k) {
        const int ln = k * 256 + tid;
        const int up = ln >> 6;
        const int h  = up & 1;
        const int el = ((up >> 3) << 6) + (((up >> 1) & 3) << 4) + c;
        const int off = el * 128 + (((h << 6) + (q << 4)) ^ ((el & 7) << 4));
        *(bf16x8*)(page + (size_t)ln * 8) = *(const bf16x8*)(ltb + off);
    }

    // t-partial reduce over the 32 row-pairs (tpart layout unchanged)
    if (tid < 128) {
        float sum = 0.f;
        #pragma unroll
        for (int mm = 0; mm < 32; ++mm) sum += ptl[mm * 129 + tid];
        tpart[((size_t)(kc * 8 + dt)) * 512 + e0 + tid] = sum;
    }
}

// ---------------------------------------------------------------------------
// K1c: t[kc][e] = sum over valid dt of tpart[kc][dt][e]
// ---------------------------------------------------------------------------
__global__ __launch_bounds__(256)
void t_reduce(const float* __restrict__ tpart, float* __restrict__ Tv) {
    const int idx = blockIdx.x * 256 + threadIdx.x;   // 131072 total
    const int kc = idx >> 9, e = idx & 511;
    const int ct = e >> 7;
    float s = 0.f;
    for (int dt = ct << 1; dt < 8; ++dt)
        s += tpart[((size_t)(kc * 8 + dt)) * 512 + e];
    Tv[idx] = s;
}

// ---------------------------------------------------------------------------
// K2: main GEMM. A fragments (Xp, 64 bf16x8 = 128 VGPR) loaded ONCE from
// global into registers in the prologue (Xp is 1 MB -> L2/L3-resident);
// only B pages go through LDS (global_load_lds, double-buffered, counted
// vmcnt(4)). LDS traffic per step drops 96 KB -> 48 KB, below the MFMA
// floor (round-3 was LDS-BW bound: 64 KB reads + 32 KB writes/step).
// ---------------------------------------------------------------------------
__global__ __launch_bounds__(256, 2)
void gml2_main(const __hip_bfloat16* __restrict__ Xp,
               const __hip_bfloat16* __restrict__ Bp,
               const float* __restrict__ Tv,
               float* __restrict__ Out) {
    __shared__ __align__(16) char bbuf[2][16384];   // B page double-buffer
    __shared__ float osum[2][128];

    const int tid = threadIdx.x;
    const int bx  = blockIdx.x;
    // XCD swizzle: all 8 row-tiles of a class on one XCD -> pages L2-resident
    const int xcd = bx & 7;
    const int g   = bx >> 3;
    const int kc  = xcd * 32 + (g >> 3);
    const int mt  = g & 7;

    const int lane = tid & 63;
    const int wave = tid >> 6;
    const int wmg  = wave & 1;      // row 64-group
    const int wng  = wave >> 1;     // col 64-group
    const int c    = lane & 15;
    const int q    = lane >> 4;

    const __bf16* pA = (const __bf16*)Xp + (size_t)(mt * 8) * STEP_ELEMS;
    const __bf16* pB = (const __bf16*)Bp + (size_t)kc * CLASS_ELEMS;

    // Tv preload: FOLD is pure VALU
    float tvr[4][4];
    #pragma unroll
    for (int ct4 = 0; ct4 < 4; ++ct4)
        #pragma unroll
        for (int ni = 0; ni < 4; ++ni)
            tvr[ct4][ni] = Tv[kc * 512 + ct4 * 128 + wng * 64 + ni * 16 + c];

    // A fragments: all 8 k-chunks, resident in VGPRs for the whole kernel.
    // (the wave's wmg-half of each A page; waves (wmg,0)/(wmg,1) duplicate
    // the load -> ~0.5 GB extra L2 reads total, trivial vs the LDS savings)
    bf16x8 fa[8][4][2];
    #pragma unroll
    for (int kch = 0; kch < 8; ++kch)
        #pragma unroll
        for (int mi = 0; mi < 4; ++mi)
            #pragma unroll
            for (int h = 0; h < 2; ++h)
                fa[kch][mi][h] = *(const bf16x8*)(pA + (size_t)kch * STEP_ELEMS
                                  + ((((wmg * 4 + mi) * 2 + h) * 64) + lane) * 8);

    f32x4 acc[4][4];
    #pragma unroll
    for (int mi = 0; mi < 4; ++mi)
        #pragma unroll
        for (int ni = 0; ni < 4; ++ni)
            acc[mi][ni] = (f32x4){0.f, 0.f, 0.f, 0.f};
    float rsum[16];
    #pragma unroll
    for (int i = 0; i < 16; ++i) rsum[i] = 0.f;

// stage B page SP into buffer BUF: 4 global_load_lds_dwordx4 per wave
#define STAGE_B(BUF, SP) {                                                     \
    const char* gb_ = (const char*)(pB + (size_t)(SP) * STEP_ELEMS);           \
    char* lb_ = &bbuf[BUF][0];                                                 \
    _Pragma("unroll") for (int i_ = 0; i_ < 4; ++i_) {                         \
        const int ch_ = (wave * 4 + i_) * 1024;                                \
        __builtin_amdgcn_global_load_lds(                                      \
            (const __attribute__((address_space(1))) void*)(gb_ + ch_ + lane * 16), \
            (__attribute__((address_space(3))) void*)(lb_ + ch_), 16, 0, 0);   \
    } }

    // fold: subtract t and square-accumulate; C/D layout col=c(e), row=q*4+r(b)
#define FOLD(CT) {                                                             \
    _Pragma("unroll") for (int mi = 0; mi < 4; ++mi)                           \
    _Pragma("unroll") for (int ni = 0; ni < 4; ++ni)                           \
    _Pragma("unroll") for (int r = 0; r < 4; ++r) {                            \
        float y_ = acc[mi][ni][r] - tvr[CT][ni];                               \
        rsum[mi * 4 + r] += y_ * y_;                                           \
        acc[mi][ni][r] = 0.f; } }

    STAGE_B(0, 0);

    #pragma unroll
    for (int s = 0; s < NSTEPS; ++s) {
        const int cur = s & 1;
        const int kch = kch_of(s);        // compile-time (loop fully unrolled)
        // fold boundaries (8, 14, 18): pure VALU, overlaps staging latency
        if (s == 8)       { FOLD(0); }
        else if (s == 14) { FOLD(1); }
        else if (s == 18) { FOLD(2); }

        if (s + 1 < NSTEPS) {
            STAGE_B(cur ^ 1, s + 1);
            // wait until only the 4 just-issued next-page loads remain:
            // buf[cur] (and the prologue A/Tv burst at s=0) fully landed
            asm volatile("s_waitcnt vmcnt(4)" ::: "memory");
        } else {
            asm volatile("s_waitcnt vmcnt(0)" ::: "memory");
        }
        __builtin_amdgcn_s_barrier();      // all waves: buf[cur] ready

        bf16x8 fb[4][2];
        #pragma unroll
        for (int ni = 0; ni < 4; ++ni)
            #pragma unroll
            for (int h = 0; h < 2; ++h)
                fb[ni][h] = *(const bf16x8*)(&bbuf[cur][0]
                              + ((((wng * 4 + ni) * 2 + h) * 64) + lane) * 16);

        #pragma unroll
        for (int h = 0; h < 2; ++h)
            #pragma unroll
            for (int mi = 0; mi < 4; ++mi)
                #pragma unroll
                for (int ni = 0; ni < 4; ++ni)
                    acc[mi][ni] = __builtin_amdgcn_mfma_f32_16x16x32_bf16(
                        fa[kch][mi][h], fb[ni][h], acc[mi][ni], 0, 0, 0);

        __builtin_amdgcn_s_barrier();      // all waves done reading buf[cur]
    }
    FOLD(3);

    // reduce the 16 e-lanes of each quad
    #pragma unroll
    for (int i = 0; i < 16; ++i) {
        float v = rsum[i];
        v += __shfl_xor(v, 1, 64);
        v += __shfl_xor(v, 2, 64);
        v += __shfl_xor(v, 4, 64);
        v += __shfl_xor(v, 8, 64);
        rsum[i] = v;
    }
    if (c == 0) {
        #pragma unroll
        for (int mi = 0; mi < 4; ++mi)
            #pragma unroll
            for (int r = 0; r < 4; ++r)
                osum[wng][wmg * 64 + mi * 16 + q * 4 + r] = rsum[mi * 4 + r];
    }
    __syncthreads();
    if (tid < 128) {
        float v = osum[0][tid] + osum[1][tid];
        Out[(size_t)(mt * 128 + tid) * KC_SZ + kc] = sqrtf(v);
    }
}

// ---------------------------------------------------------------------------
// Fallback (round-2 kernel, proven, ws-independent).
// ---------------------------------------------------------------------------
#define FLDA 40
#define BM 128
#define BN 128
__device__ __forceinline__ void fstep_map(int s, int& ct, int& k0) {
    if (s < 16)      { ct = 0; k0 = s * 32; }
    else if (s < 28) { ct = 1; k0 = 128 + (s - 16) * 32; }
    else if (s < 36) { ct = 2; k0 = 256 + (s - 28) * 32; }
    else             { ct = 3; k0 = 384 + (s - 36) * 32; }
}
__global__ __launch_bounds__(256, 2)
void gml2_fallback(const float* __restrict__ X, const float* __restrict__ W,
                   const float* __restrict__ Ldiag, const float* __restrict__ Llow,
                   float* __restrict__ Out) {
    __shared__ __bf16 As[BM * FLDA];
    __shared__ __bf16 Bs[BN * FLDA];
    __shared__ float  Ws[D_SZ];
    __shared__ float  osum[2][BM];
    const int tid = threadIdx.x;
    const int bx  = blockIdx.x;
    const int xcd = bx & 7;
    const int g   = bx >> 3;
    const int kc  = xcd * 32 + (g >> 3);
    const int mt  = g & 7;
    const int lane = tid & 63, wave = tid >> 6;
    const int wm = (wave & 1) * 64, wn = (wave >> 1) * 64;
    const int c = lane & 15, q = lane >> 4;
    const int am = tid >> 1, akh = (tid & 1) << 4;
    const float* xrow = X + (size_t)(mt * BM + am) * D_SZ;
    const float* wrow = W + (size_t)kc * D_SZ;
    const int be = tid & 127, bd = (tid >> 7) << 4;
    const float* lowbase  = Llow  + (size_t)kc * NLOW;
    const float* diagbase = Ldiag + (size_t)kc * D_SZ;
    if (tid < 128) ((f32x4*)Ws)[tid] = ((const f32x4*)wrow)[tid];
    float rsum[16];
    #pragma unroll
    for (int i = 0; i < 16; ++i) rsum[i] = 0.f;
    f32x4 acc[4][4];
    #pragma unroll
    for (int mi = 0; mi < 4; ++mi)
        #pragma unroll
        for (int ni = 0; ni < 4; ++ni) acc[mi][ni] = (f32x4){0.f, 0.f, 0.f, 0.f};
    f32x4 xr[4];
    float bb[16];
    auto prefetch = [&](int s) {
        int pct, pk0; fstep_map(s, pct, pk0);
        const int pe0 = pct * BN;
        const float* xp = xrow + pk0 + akh;
        #pragma unroll
        for (int i = 0; i < 4; ++i) xr[i] = ((const f32x4*)xp)[i];
        const int e = pe0 + be, d0 = pk0 + bd;
        int tri = (d0 * (d0 - 1)) >> 1;
        if (pk0 >= pe0 + BN) {
            #pragma unroll
            for (int j = 0; j < 16; ++j) { bb[j] = lowbase[tri + e]; tri += d0 + j; }
        } else {
            #pragma unroll
            for (int j = 0; j < 16; ++j) {
                const int d = d0 + j;
                float val = 0.f;
                if (d > e)       val = lowbase[tri + e];
                else if (d == e) { float dq = diagbase[d]; val = dq * dq; }
                bb[j] = val; tri += d;
            }
        }
    };
    prefetch(0);
    __syncthreads();
    int cur_ct = 0;
    for (int s = 0; s < 40; ++s) {
        int ct, k0; fstep_map(s, ct, k0);
        if (ct != cur_ct) {
            #pragma unroll
            for (int mi = 0; mi < 4; ++mi)
                #pragma unroll
                for (int ni = 0; ni < 4; ++ni)
                    #pragma unroll
                    for (int r = 0; r < 4; ++r) {
                        float y = acc[mi][ni][r];
                        rsum[mi * 4 + r] += y * y;
                        acc[mi][ni][r] = 0.f;
                    }
            cur_ct = ct;
        }
        bf16x8 ap0, ap1;
        {
            const f32x4* wsp = (const f32x4*)&Ws[k0 + akh];
            #pragma unroll
            for (int i = 0; i < 4; ++i) {
                f32x4 wv = wsp[i];
                #pragma unroll
                for (int l = 0; l < 4; ++l) {
                    float v = xr[i][l] - wv[l];
                    int idx = i * 4 + l;
                    if (idx < 8) ap0[idx] = (__bf16)v;
                    else         ap1[idx - 8] = (__bf16)v;
                }
            }
        }
        bf16x8 bp0, bp1;
        #pragma unroll
        for (int j = 0; j < 8; ++j) { bp0[j] = (__bf16)bb[j]; bp1[j] = (__bf16)bb[j + 8]; }
        __syncthreads();
        *(bf16x8*)&As[am * FLDA + akh]     = ap0;
        *(bf16x8*)&As[am * FLDA + akh + 8] = ap1;
        *(bf16x8*)&Bs[be * FLDA + bd]      = bp0;
        *(bf16x8*)&Bs[be * FLDA + bd + 8]  = bp1;
        if (s + 1 < 40) prefetch(s + 1);
        __syncthreads();
        bf16x8 af[4], bfr[4];
        #pragma unroll
        for (int mi = 0; mi < 4; ++mi)
            af[mi] = *(const bf16x8*)&As[(wm + mi * 16 + c) * FLDA + q * 8];
        #pragma unroll
        for (int ni = 0; ni < 4; ++ni)
            bfr[ni] = *(const bf16x8*)&Bs[(wn + ni * 16 + c) * FLDA + q * 8];
        #pragma unroll
        for (int mi = 0; mi < 4; ++mi)
            #pragma unroll
            for (int ni = 0; ni < 4; ++ni)
                acc[mi][ni] = __builtin_amdgcn_mfma_f32_16x16x32_bf16(
                    af[mi], bfr[ni], acc[mi][ni], 0, 0, 0);
    }
    #pragma unroll
    for (int mi = 0; mi < 4; ++mi)
        #pragma unroll
        for (int ni = 0; ni < 4; ++ni)
            #pragma unroll
            for (int r = 0; r < 4; ++r) {
                float y = acc[mi][ni][r];
                rsum[mi * 4 + r] += y * y;
            }
    #pragma unroll
    for (int i = 0; i < 16; ++i) {
        float s = rsum[i];
        s += __shfl_xor(s, 1, 64);
        s += __shfl_xor(s, 2, 64);
        s += __shfl_xor(s, 4, 64);
        s += __shfl_xor(s, 8, 64);
        rsum[i] = s;
    }
    const int wnIdx = wave >> 1;
    if (c == 0) {
        #pragma unroll
        for (int mi = 0; mi < 4; ++mi)
            #pragma unroll
            for (int r = 0; r < 4; ++r)
                osum[wnIdx][wm + mi * 16 + q * 4 + r] = rsum[mi * 4 + r];
    }
    __syncthreads();
    if (tid < BM) {
        float s = osum[0][tid] + osum[1][tid];
        Out[(size_t)(mt * BM + tid) * KC_SZ + kc] = sqrtf(s);
    }
}

extern "C" void kernel_launch(void* const* d_in, const int* in_sizes, int n_in,
                              void* d_out, int out_size, void* d_ws, size_t ws_size,
                              hipStream_t stream) {
    const float* X  = (const float*)d_in[0];   // [1024, 512]
    const float* W  = (const float*)d_in[1];   // [256, 1, 512]
    const float* Ld = (const float*)d_in[2];   // [256, 512]
    const float* Ll = (const float*)d_in[3];   // [256, 130816]
    float* Out = (float*)d_out;                // [1024, 256]

    if (ws_size >= WS_NEED) {
        __hip_bfloat16* Bp    = (__hip_bfloat16*)d_ws;
        __hip_bfloat16* Xp    = (__hip_bfloat16*)((char*)d_ws + OFF_XP);
        float*          tpart = (float*)((char*)d_ws + OFF_TPART);
        float*          Tvv   = (float*)((char*)d_ws + OFF_T);
        prep_x  <<<dim3(256),           dim3(256), 0, stream>>>(X, Xp);
        prep_b  <<<dim3(NSTEPS, KC_SZ), dim3(256), 0, stream>>>(Ld, Ll, W, Bp, tpart);
        t_reduce<<<dim3(512),           dim3(256), 0, stream>>>(tpart, Tvv);
        gml2_main<<<dim3(KC_SZ * 8),    dim3(256), 0, stream>>>(Xp, Bp, Tvv, Out);
    } else {
        gml2_fallback<<<dim3(KC_SZ * 8), dim3(256), 0, stream>>>(X, W, Ld, Ll, Out);
    }
}

// Round 5
// 468.971 us; speedup vs baseline: 1.2856x; 1.2856x over previous
//
#include <hip/hip_runtime.h>
#include <hip/hip_bf16.h>
#include <math.h>

// Problem constants
#define B_SZ   1024
#define D_SZ   512
#define KC_SZ  256
#define NLOW   130816            // 512*511/2

// B pages: per class, 20 K-step pages of 16 KB, stored in per-wave MFMA
// fragment order: line = ((wng*4+ni)*2+h)*64 + lane, lane = q*16+c,
// value[j] = L[d][e], e = wng*64+ni*16+c, d_local = h*32+q*8+j.
#define STEP_ELEMS  8192
#define NSTEPS      20           // 8+6+4+2 triangular K-steps
#define CLASS_ELEMS (NSTEPS * STEP_ELEMS)   // 320 KB/class

// Workspace layout (bytes)
#define OFF_XP     (size_t)(KC_SZ * CLASS_ELEMS * 2)        // 83886080
#define OFF_TPART  (OFF_XP + 64 * STEP_ELEMS * 2)           // +1 MiB
#define OFF_T      (OFF_TPART + (size_t)KC_SZ * 8 * 512 * 4)// +4 MiB
#define WS_NEED    (OFF_T + (size_t)KC_SZ * 512 * 4)        // ~85.5 MiB

typedef __attribute__((ext_vector_type(4))) float  f32x4;
typedef __attribute__((ext_vector_type(4), aligned(4))) float f32x4u; // align-4 vector load
typedef __attribute__((ext_vector_type(8))) __bf16 bf16x8;

// steps before col-tile ct
__device__ __forceinline__ int sbase_of(int ct) { return ct * (9 - ct); }
// s -> dt (also the A-page k-chunk)
__device__ __forceinline__ int kch_of(int s) {
    return (s < 8) ? s : (s < 14) ? s - 6 : (s < 18) ? s - 10 : s - 12;
}

// ---------------------------------------------------------------------------
// K1a: X pages, bf16, A-fragment order. 256 blocks (pg 0..63 x quarter 0..3).
// ---------------------------------------------------------------------------
__global__ __launch_bounds__(256)
void prep_x(const float* __restrict__ X, __hip_bfloat16* __restrict__ Xp) {
    const int bx  = blockIdx.x;
    const int pg  = bx >> 2;             // mt*8 + kch
    const int mt  = pg >> 3, kch = pg & 7;
    __bf16* out = (__bf16*)Xp + (size_t)pg * STEP_ELEMS;
    const int line = threadIdx.x + (bx & 3) * 256;   // 0..1023
    const int wmg = line >> 9, mi = (line >> 7) & 3, h = (line >> 6) & 1;
    const int lane = line & 63, q = lane >> 4, c = lane & 15;
    const int row = mt * 128 + wmg * 64 + mi * 16 + c;
    const float* src = X + (size_t)row * D_SZ + kch * 64 + h * 32 + q * 8;
    f32x4 v0 = ((const f32x4*)src)[0];
    f32x4 v1 = ((const f32x4*)src)[1];
    bf16x8 p;
    #pragma unroll
    for (int j = 0; j < 4; ++j) { p[j] = (__bf16)v0[j]; p[j + 4] = (__bf16)v1[j]; }
    *(bf16x8*)(out + line * 8) = p;
}

// ---------------------------------------------------------------------------
// K1b: one block per (class, page). Vector f32x4 global reads, bf16
// transposed LDS tile [e][d] with XOR-swizzled 16B blocks so the fragment
// read is a single conflict-free ds_read_b128. t-partials from the f32
// registers (fp32 exact), tpart layout unchanged.
// ---------------------------------------------------------------------------
__global__ __launch_bounds__(256)
void prep_b(const float* __restrict__ Ldiag,
            const float* __restrict__ Llow,
            const float* __restrict__ W,
            __hip_bfloat16* __restrict__ Bp,
            float* __restrict__ tpart) {
    __shared__ __bf16 Lt[128 * 64];      // [e_local][d_local], 16B-block XOR swizzle
    __shared__ float  ptl[32 * 129];     // [m][e_local], padded: bank=(m+e)%32

    const int s  = blockIdx.x;           // page 0..19
    const int kc = blockIdx.y;           // class
    const int ct = (s < 8) ? 0 : (s < 14) ? 1 : (s < 18) ? 2 : 3;
    const int dt = kch_of(s);
    const int e0 = ct << 7, d0 = dt << 6;

    const int tid = threadIdx.x;
    const int m   = tid & 31;            // d row-pair index
    const int seg = tid >> 5;            // e 16-chunk index
    const int es  = seg << 4;            // e_local chunk start
    const int dg0 = d0 + 2 * m;          // global d of row 0 (row 1 = dg0+1)

    // classify this thread's 16-e chunk:
    // 0 = pure strict-lower (vector loads), 1 = straddles diagonal, 2 = zero
    int cls;
    if (dt >= 2 * ct + 2)      cls = 0;
    else if (dt == 2 * ct + 1) cls = (seg < 4) ? 0 : 1;
    else                       cls = (seg < 4) ? 1 : 2;

    const float* lowb = Llow + (size_t)kc * NLOW;
    const float2 wv = *(const float2*)(W + (size_t)kc * D_SZ + dg0);

    float v0[16], v1[16];
    if (cls == 0) {
        const int t0 = (dg0 * (dg0 - 1)) >> 1;       // tri(dg0)
        const int t1 = t0 + dg0;                     // tri(dg0+1)
        const float* s0 = lowb + t0 + e0 + es;
        const float* s1 = lowb + t1 + e0 + es;
        #pragma unroll
        for (int i = 0; i < 4; ++i) {
            f32x4u a = ((const f32x4u*)s0)[i];
            f32x4u b = ((const f32x4u*)s1)[i];
            #pragma unroll
            for (int j = 0; j < 4; ++j) { v0[i * 4 + j] = a[j]; v1[i * 4 + j] = b[j]; }
        }
    } else if (cls == 1) {
        const int t0 = (dg0 * (dg0 - 1)) >> 1;
        const int t1 = t0 + dg0;
        const float* diagb = Ldiag + (size_t)kc * D_SZ;
        float q0 = diagb[dg0],     q1 = diagb[dg0 + 1];
        q0 *= q0; q1 *= q1;
        #pragma unroll
        for (int j = 0; j < 16; ++j) {
            const int eg = e0 + es + j;
            v0[j] = (eg < dg0)     ? lowb[t0 + eg] : ((eg == dg0)     ? q0 : 0.f);
            v1[j] = (eg < dg0 + 1) ? lowb[t1 + eg] : ((eg == dg0 + 1) ? q1 : 0.f);
        }
    } else {
        #pragma unroll
        for (int j = 0; j < 16; ++j) { v0[j] = 0.f; v1[j] = 0.f; }
    }

    // transposed bf16 pair writes (conflict-free) + fp32 t-partials
    char* ltb = (char*)Lt;
    #pragma unroll
    for (int j = 0; j < 16; ++j) {
        const int el = es + j;
        union { __bf16 h[2]; unsigned u; } pk;
        pk.h[0] = (__bf16)v0[j];
        pk.h[1] = (__bf16)v1[j];
        const int off = el * 128 + ((4 * m) ^ ((el & 7) << 4));
        *(unsigned*)(ltb + off) = pk.u;
        ptl[m * 129 + el] = wv.x * v0[j] + wv.y * v1[j];
    }
    __syncthreads();

    // fragment-order page out: 4 lines/thread, one ds_read_b128 + 16B store each
    __bf16* page = (__bf16*)Bp + (size_t)kc * CLASS_ELEMS + (size_t)s * STEP_ELEMS;
    const int lane = tid & 63, q = lane >> 4, c = lane & 15;
    #pragma unroll
    for (int k = 0; k < 4; ++k) {
        const int ln = k * 256 + tid;
        const int up = ln >> 6;
        const int h  = up & 1;
        const int el = ((up >> 3) << 6) + (((up >> 1) & 3) << 4) + c;
        const int off = el * 128 + (((h << 6) + (q << 4)) ^ ((el & 7) << 4));
        *(bf16x8*)(page + (size_t)ln * 8) = *(const bf16x8*)(ltb + off);
    }

    // t-partial reduce over the 32 row-pairs (tpart layout unchanged)
    if (tid < 128) {
        float sum = 0.f;
        #pragma unroll
        for (int mm = 0; mm < 32; ++mm) sum += ptl[mm * 129 + tid];
        tpart[((size_t)(kc * 8 + dt)) * 512 + e0 + tid] = sum;
    }
}

// ---------------------------------------------------------------------------
// K1c: t[kc][e] = sum over valid dt of tpart[kc][dt][e]
// ---------------------------------------------------------------------------
__global__ __launch_bounds__(256)
void t_reduce(const float* __restrict__ tpart, float* __restrict__ Tv) {
    const int idx = blockIdx.x * 256 + threadIdx.x;   // 131072 total
    const int kc = idx >> 9, e = idx & 511;
    const int ct = e >> 7;
    float s = 0.f;
    for (int dt = ct << 1; dt < 8; ++dt)
        s += tpart[((size_t)(kc * 8 + dt)) * 512 + e];
    Tv[idx] = s;
}

// ---------------------------------------------------------------------------
// K2: main GEMM. A fragments resident in VGPRs as EIGHT NAMED [4][2] arrays
// (128 B each -- the shape SROA provably promotes; round-4's single
// fa[8][4][2] 1 KB aggregate was kept in scratch -> 1.3 GB spill traffic).
// Tv lives in LDS (frees 16 pinned VGPRs). Only B pages stream through LDS
// (global_load_lds, double-buffered, counted vmcnt(4)). LDS reads drop to
// 32 KB/step (B only), below the 41 us MFMA floor.
// Pinned VGPR: fa 128 + acc 64 + rsum 16 = 208; peak ~232 < 256.
// ---------------------------------------------------------------------------
__global__ __launch_bounds__(256, 2)
void gml2_main(const __hip_bfloat16* __restrict__ Xp,
               const __hip_bfloat16* __restrict__ Bp,
               const float* __restrict__ Tv,
               float* __restrict__ Out) {
    __shared__ __align__(16) char bbuf[2][16384];   // B page double-buffer
    __shared__ float tvs[512];
    __shared__ float osum[2][128];

    const int tid = threadIdx.x;
    const int bx  = blockIdx.x;
    // XCD swizzle: all 8 row-tiles of a class on one XCD -> pages L2-resident
    const int xcd = bx & 7;
    const int g   = bx >> 3;
    const int kc  = xcd * 32 + (g >> 3);
    const int mt  = g & 7;

    const int lane = tid & 63;
    const int wave = tid >> 6;
    const int wmg  = wave & 1;      // row 64-group
    const int wng  = wave >> 1;     // col 64-group
    const int c    = lane & 15;
    const int q    = lane >> 4;

    const __bf16* pA = (const __bf16*)Xp + (size_t)(mt * 8) * STEP_ELEMS;
    const __bf16* pB = (const __bf16*)Bp + (size_t)kc * CLASS_ELEMS;

    // Tv -> LDS (read at fold time; q-groups broadcast, conflict-free)
    if (tid < 128) ((f32x4*)tvs)[tid] = ((const f32x4*)(Tv + kc * 512))[tid];

    // A fragments: 8 named [4][2] arrays, register-resident for the kernel.
    bf16x8 fa0[4][2], fa1[4][2], fa2[4][2], fa3[4][2],
           fa5[4][2], fa4[4][2], fa6[4][2], fa7[4][2];
#define LOAD_FA(NAME, KCH) {                                                   \
    const __bf16* p_ = pA + (size_t)(KCH) * STEP_ELEMS;                        \
    _Pragma("unroll") for (int mi = 0; mi < 4; ++mi)                           \
    _Pragma("unroll") for (int h = 0; h < 2; ++h)                              \
        NAME[mi][h] = *(const bf16x8*)(p_ +                                    \
            ((((wmg * 4 + mi) * 2 + h) * 64) + lane) * 8); }
    LOAD_FA(fa0, 0) LOAD_FA(fa1, 1) LOAD_FA(fa2, 2) LOAD_FA(fa3, 3)
    LOAD_FA(fa4, 4) LOAD_FA(fa5, 5) LOAD_FA(fa6, 6) LOAD_FA(fa7, 7)

    f32x4 acc[4][4];
    #pragma unroll
    for (int mi = 0; mi < 4; ++mi)
        #pragma unroll
        for (int ni = 0; ni < 4; ++ni)
            acc[mi][ni] = (f32x4){0.f, 0.f, 0.f, 0.f};
    float rsum[16];
    #pragma unroll
    for (int i = 0; i < 16; ++i) rsum[i] = 0.f;

// stage B page SP into buffer BUF: 4 global_load_lds_dwordx4 per wave
#define STAGE_B(BUF, SP) {                                                     \
    const char* gb_ = (const char*)(pB + (size_t)(SP) * STEP_ELEMS);           \
    char* lb_ = &bbuf[BUF][0];                                                 \
    _Pragma("unroll") for (int i_ = 0; i_ < 4; ++i_) {                         \
        const int ch_ = (wave * 4 + i_) * 1024;                                \
        __builtin_amdgcn_global_load_lds(                                      \
            (const __attribute__((address_space(1))) void*)(gb_ + ch_ + lane * 16), \
            (__attribute__((address_space(3))) void*)(lb_ + ch_), 16, 0, 0);   \
    } }

// one K-step with literal step index S and named resident A array FA
#define GSTEP(S, FA) {                                                         \
    if ((S) + 1 < NSTEPS) {                                                    \
        STAGE_B(((S) & 1) ^ 1, (S) + 1);                                       \
        asm volatile("s_waitcnt vmcnt(4)" ::: "memory");                       \
    } else {                                                                   \
        asm volatile("s_waitcnt vmcnt(0)" ::: "memory");                       \
    }                                                                          \
    __builtin_amdgcn_s_barrier();                                              \
    bf16x8 fb[4][2];                                                           \
    _Pragma("unroll") for (int ni = 0; ni < 4; ++ni)                           \
    _Pragma("unroll") for (int h = 0; h < 2; ++h)                              \
        fb[ni][h] = *(const bf16x8*)(&bbuf[(S) & 1][0] +                       \
            ((((wng * 4 + ni) * 2 + h) * 64) + lane) * 16);                    \
    _Pragma("unroll") for (int h = 0; h < 2; ++h)                              \
    _Pragma("unroll") for (int mi = 0; mi < 4; ++mi)                           \
    _Pragma("unroll") for (int ni = 0; ni < 4; ++ni)                           \
        acc[mi][ni] = __builtin_amdgcn_mfma_f32_16x16x32_bf16(                 \
            FA[mi][h], fb[ni][h], acc[mi][ni], 0, 0, 0);                       \
    __builtin_amdgcn_s_barrier(); }

    // fold: subtract t and square-accumulate; C/D layout col=c(e), row=q*4+r(b)
#define FOLD(CT) {                                                             \
    float tv_[4];                                                              \
    _Pragma("unroll") for (int ni = 0; ni < 4; ++ni)                           \
        tv_[ni] = tvs[(CT) * 128 + wng * 64 + ni * 16 + c];                    \
    _Pragma("unroll") for (int mi = 0; mi < 4; ++mi)                           \
    _Pragma("unroll") for (int ni = 0; ni < 4; ++ni)                           \
    _Pragma("unroll") for (int r = 0; r < 4; ++r) {                            \
        float y_ = acc[mi][ni][r] - tv_[ni];                                   \
        rsum[mi * 4 + r] += y_ * y_;                                           \
        acc[mi][ni][r] = 0.f; } }

    STAGE_B(0, 0);

    GSTEP(0,  fa0) GSTEP(1,  fa1) GSTEP(2,  fa2) GSTEP(3,  fa3)
    GSTEP(4,  fa4) GSTEP(5,  fa5) GSTEP(6,  fa6) GSTEP(7,  fa7)
    FOLD(0)
    GSTEP(8,  fa2) GSTEP(9,  fa3) GSTEP(10, fa4) GSTEP(11, fa5)
    GSTEP(12, fa6) GSTEP(13, fa7)
    FOLD(1)
    GSTEP(14, fa4) GSTEP(15, fa5) GSTEP(16, fa6) GSTEP(17, fa7)
    FOLD(2)
    GSTEP(18, fa6) GSTEP(19, fa7)
    FOLD(3)

    // reduce the 16 e-lanes of each quad
    #pragma unroll
    for (int i = 0; i < 16; ++i) {
        float v = rsum[i];
        v += __shfl_xor(v, 1, 64);
        v += __shfl_xor(v, 2, 64);
        v += __shfl_xor(v, 4, 64);
        v += __shfl_xor(v, 8, 64);
        rsum[i] = v;
    }
    if (c == 0) {
        #pragma unroll
        for (int mi = 0; mi < 4; ++mi)
            #pragma unroll
            for (int r = 0; r < 4; ++r)
                osum[wng][wmg * 64 + mi * 16 + q * 4 + r] = rsum[mi * 4 + r];
    }
    __syncthreads();
    if (tid < 128) {
        float v = osum[0][tid] + osum[1][tid];
        Out[(size_t)(mt * 128 + tid) * KC_SZ + kc] = sqrtf(v);
    }
}

// ---------------------------------------------------------------------------
// Fallback (round-2 kernel, proven, ws-independent).
// ---------------------------------------------------------------------------
#define FLDA 40
#define BM 128
#define BN 128
__device__ __forceinline__ void fstep_map(int s, int& ct, int& k0) {
    if (s < 16)      { ct = 0; k0 = s * 32; }
    else if (s < 28) { ct = 1; k0 = 128 + (s - 16) * 32; }
    else if (s < 36) { ct = 2; k0 = 256 + (s - 28) * 32; }
    else             { ct = 3; k0 = 384 + (s - 36) * 32; }
}
__global__ __launch_bounds__(256, 2)
void gml2_fallback(const float* __restrict__ X, const float* __restrict__ W,
                   const float* __restrict__ Ldiag, const float* __restrict__ Llow,
                   float* __restrict__ Out) {
    __shared__ __bf16 As[BM * FLDA];
    __shared__ __bf16 Bs[BN * FLDA];
    __shared__ float  Ws[D_SZ];
    __shared__ float  osum[2][BM];
    const int tid = threadIdx.x;
    const int bx  = blockIdx.x;
    const int xcd = bx & 7;
    const int g   = bx >> 3;
    const int kc  = xcd * 32 + (g >> 3);
    const int mt  = g & 7;
    const int lane = tid & 63, wave = tid >> 6;
    const int wm = (wave & 1) * 64, wn = (wave >> 1) * 64;
    const int c = lane & 15, q = lane >> 4;
    const int am = tid >> 1, akh = (tid & 1) << 4;
    const float* xrow = X + (size_t)(mt * BM + am) * D_SZ;
    const float* wrow = W + (size_t)kc * D_SZ;
    const int be = tid & 127, bd = (tid >> 7) << 4;
    const float* lowbase  = Llow  + (size_t)kc * NLOW;
    const float* diagbase = Ldiag + (size_t)kc * D_SZ;
    if (tid < 128) ((f32x4*)Ws)[tid] = ((const f32x4*)wrow)[tid];
    float rsum[16];
    #pragma unroll
    for (int i = 0; i < 16; ++i) rsum[i] = 0.f;
    f32x4 acc[4][4];
    #pragma unroll
    for (int mi = 0; mi < 4; ++mi)
        #pragma unroll
        for (int ni = 0; ni < 4; ++ni) acc[mi][ni] = (f32x4){0.f, 0.f, 0.f, 0.f};
    f32x4 xr[4];
    float bb[16];
    auto prefetch = [&](int s) {
        int pct, pk0; fstep_map(s, pct, pk0);
        const int pe0 = pct * BN;
        const float* xp = xrow + pk0 + akh;
        #pragma unroll
        for (int i = 0; i < 4; ++i) xr[i] = ((const f32x4*)xp)[i];
        const int e = pe0 + be, d0 = pk0 + bd;
        int tri = (d0 * (d0 - 1)) >> 1;
        if (pk0 >= pe0 + BN) {
            #pragma unroll
            for (int j = 0; j < 16; ++j) { bb[j] = lowbase[tri + e]; tri += d0 + j; }
        } else {
            #pragma unroll
            for (int j = 0; j < 16; ++j) {
                const int d = d0 + j;
                float val = 0.f;
                if (d > e)       val = lowbase[tri + e];
                else if (d == e) { float dq = diagbase[d]; val = dq * dq; }
                bb[j] = val; tri += d;
            }
        }
    };
    prefetch(0);
    __syncthreads();
    int cur_ct = 0;
    for (int s = 0; s < 40; ++s) {
        int ct, k0; fstep_map(s, ct, k0);
        if (ct != cur_ct) {
            #pragma unroll
            for (int mi = 0; mi < 4; ++mi)
                #pragma unroll
                for (int ni = 0; ni < 4; ++ni)
                    #pragma unroll
                    for (int r = 0; r < 4; ++r) {
                        float y = acc[mi][ni][r];
                        rsum[mi * 4 + r] += y * y;
                        acc[mi][ni][r] = 0.f;
                    }
            cur_ct = ct;
        }
        bf16x8 ap0, ap1;
        {
            const f32x4* wsp = (const f32x4*)&Ws[k0 + akh];
            #pragma unroll
            for (int i = 0; i < 4; ++i) {
                f32x4 wv = wsp[i];
                #pragma unroll
                for (int l = 0; l < 4; ++l) {
                    float v = xr[i][l] - wv[l];
                    int idx = i * 4 + l;
                    if (idx < 8) ap0[idx] = (__bf16)v;
                    else         ap1[idx - 8] = (__bf16)v;
                }
            }
        }
        bf16x8 bp0, bp1;
        #pragma unroll
        for (int j = 0; j < 8; ++j) { bp0[j] = (__bf16)bb[j]; bp1[j] = (__bf16)bb[j + 8]; }
        __syncthreads();
        *(bf16x8*)&As[am * FLDA + akh]     = ap0;
        *(bf16x8*)&As[am * FLDA + akh + 8] = ap1;
        *(bf16x8*)&Bs[be * FLDA + bd]      = bp0;
        *(bf16x8*)&Bs[be * FLDA + bd + 8]  = bp1;
        if (s + 1 < 40) prefetch(s + 1);
        __syncthreads();
        bf16x8 af[4], bfr[4];
        #pragma unroll
        for (int mi = 0; mi < 4; ++mi)
            af[mi] = *(const bf16x8*)&As[(wm + mi * 16 + c) * FLDA + q * 8];
        #pragma unroll
        for (int ni = 0; ni < 4; ++ni)
            bfr[ni] = *(const bf16x8*)&Bs[(wn + ni * 16 + c) * FLDA + q * 8];
        #pragma unroll
        for (int mi = 0; mi < 4; ++mi)
            #pragma unroll
            for (int ni = 0; ni < 4; ++ni)
                acc[mi][ni] = __builtin_amdgcn_mfma_f32_16x16x32_bf16(
                    af[mi], bfr[ni], acc[mi][ni], 0, 0, 0);
    }
    #pragma unroll
    for (int mi = 0; mi < 4; ++mi)
        #pragma unroll
        for (int ni = 0; ni < 4; ++ni)
            #pragma unroll
            for (int r = 0; r < 4; ++r) {
                float y = acc[mi][ni][r];
                rsum[mi * 4 + r] += y * y;
            }
    #pragma unroll
    for (int i = 0; i < 16; ++i) {
        float s = rsum[i];
        s += __shfl_xor(s, 1, 64);
        s += __shfl_xor(s, 2, 64);
        s += __shfl_xor(s, 4, 64);
        s += __shfl_xor(s, 8, 64);
        rsum[i] = s;
    }
    const int wnIdx = wave >> 1;
    if (c == 0) {
        #pragma unroll
        for (int mi = 0; mi < 4; ++mi)
            #pragma unroll
            for (int r = 0; r < 4; ++r)
                osum[wnIdx][wm + mi * 16 + q * 4 + r] = rsum[mi * 4 + r];
    }
    __syncthreads();
    if (tid < BM) {
        float s = osum[0][tid] + osum[1][tid];
        Out[(size_t)(mt * BM + tid) * KC_SZ + kc] = sqrtf(s);
    }
}

extern "C" void kernel_launch(void* const* d_in, const int* in_sizes, int n_in,
                              void* d_out, int out_size, void* d_ws, size_t ws_size,
                              hipStream_t stream) {
    const float* X  = (const float*)d_in[0];   // [1024, 512]
    const float* W  = (const float*)d_in[1];   // [256, 1, 512]
    const float* Ld = (const float*)d_in[2];   // [256, 512]
    const float* Ll = (const float*)d_in[3];   // [256, 130816]
    float* Out = (float*)d_out;                // [1024, 256]

    if (ws_size >= WS_NEED) {
        __hip_bfloat16* Bp    = (__hip_bfloat16*)d_ws;
        __hip_bfloat16* Xp    = (__hip_bfloat16*)((char*)d_ws + OFF_XP);
        float*          tpart = (float*)((char*)d_ws + OFF_TPART);
        float*          Tvv   = (float*)((char*)d_ws + OFF_T);
        prep_x  <<<dim3(256),           dim3(256), 0, stream>>>(X, Xp);
        prep_b  <<<dim3(NSTEPS, KC_SZ), dim3(256), 0, stream>>>(Ld, Ll, W, Bp, tpart);
        t_reduce<<<dim3(512),           dim3(256), 0, stream>>>(tpart, Tvv);
        gml2_main<<<dim3(KC_SZ * 8),    dim3(256), 0, stream>>>(Xp, Bp, Tvv, Out);
    } else {
        gml2_fallback<<<dim3(KC_SZ * 8), dim3(256), 0, stream>>>(X, W, Ld, Ll, Out);
    }
}

// Round 6
// 347.042 us; speedup vs baseline: 1.7373x; 1.3513x over previous
//
#include <hip/hip_runtime.h>
#include <hip/hip_bf16.h>
#include <math.h>

// Problem constants
#define B_SZ   1024
#define D_SZ   512
#define KC_SZ  256
#define NLOW   130816            // 512*511/2

// B pages: per class, 20 K-step pages of 16 KB, stored in per-wave MFMA
// fragment order: line = ((wng*4+ni)*2+h)*64 + lane, lane = q*16+c,
// value[j] = L[d][e], e = wng*64+ni*16+c, d_local = h*32+q*8+j.
#define STEP_ELEMS  8192
#define NSTEPS      20           // 8+6+4+2 triangular K-steps
#define CLASS_ELEMS (NSTEPS * STEP_ELEMS)   // 320 KB/class

// Workspace layout (bytes)
#define OFF_XP     (size_t)(KC_SZ * CLASS_ELEMS * 2)        // 83886080
#define OFF_TPART  (OFF_XP + 64 * STEP_ELEMS * 2)           // +1 MiB
#define OFF_T      (OFF_TPART + (size_t)KC_SZ * 8 * 512 * 4)// +4 MiB
#define WS_NEED    (OFF_T + (size_t)KC_SZ * 512 * 4)        // ~85.5 MiB

typedef __attribute__((ext_vector_type(4))) float  f32x4;
typedef __attribute__((ext_vector_type(4), aligned(4))) float f32x4u; // align-4 vector load
typedef __attribute__((ext_vector_type(8))) __bf16 bf16x8;

// steps before col-tile ct
__device__ __forceinline__ int sbase_of(int ct) { return ct * (9 - ct); }
// s -> dt (also the A-page k-chunk)
__device__ __forceinline__ int kch_of(int s) {
    return (s < 8) ? s : (s < 14) ? s - 6 : (s < 18) ? s - 10 : s - 12;
}

// ---------------------------------------------------------------------------
// K1: fused prep. Blocks [0,64): X pages (bf16, A-fragment order).
// Blocks [64, 64+20*256): B pages + t-partials (one block per class,page).
// Zero-half pages (dt == 2*ct, s in {0,8,14,18}): upper e-half (e_local>=64)
// is identically zero -> only the lower 8 KB is written; main never reads
// the rest.
// ---------------------------------------------------------------------------
__global__ __launch_bounds__(256)
void prep_all(const float* __restrict__ X,
              const float* __restrict__ Ldiag,
              const float* __restrict__ Llow,
              const float* __restrict__ W,
              __hip_bfloat16* __restrict__ Xp,
              __hip_bfloat16* __restrict__ Bp,
              float* __restrict__ tpart) {
    __shared__ __bf16 Lt[128 * 64];      // [e_local][d_local], 16B-block XOR swizzle
    __shared__ float  ptl[32 * 129];     // [m][e_local], padded: bank=(m+e)%32

    const int bx  = blockIdx.x;
    const int tid = threadIdx.x;

    if (bx < 64) {
        // ---- prep_x: page pg = bx, 4 lines per thread ----
        const int pg  = bx;              // mt*8 + kch
        const int mt  = pg >> 3, kch = pg & 7;
        __bf16* out = (__bf16*)Xp + (size_t)pg * STEP_ELEMS;
        #pragma unroll
        for (int i = 0; i < 4; ++i) {
            const int line = tid + i * 256;          // 0..1023
            const int wmg = line >> 9, mi = (line >> 7) & 3, h = (line >> 6) & 1;
            const int lane = line & 63, q = lane >> 4, c = lane & 15;
            const int row = mt * 128 + wmg * 64 + mi * 16 + c;
            const float* src = X + (size_t)row * D_SZ + kch * 64 + h * 32 + q * 8;
            f32x4 v0 = ((const f32x4*)src)[0];
            f32x4 v1 = ((const f32x4*)src)[1];
            bf16x8 p;
            #pragma unroll
            for (int j = 0; j < 4; ++j) { p[j] = (__bf16)v0[j]; p[j + 4] = (__bf16)v1[j]; }
            *(bf16x8*)(out + line * 8) = p;
        }
        return;
    }

    // ---- prep_b: page s of class kc ----
    const int idx = bx - 64;
    const int s   = idx % 20;
    const int kc  = idx / 20;
    const int ct = (s < 8) ? 0 : (s < 14) ? 1 : (s < 18) ? 2 : 3;
    const int dt = kch_of(s);
    const int e0 = ct << 7, d0 = dt << 6;
    const bool zpage = (dt == 2 * ct);   // upper e-half all-zero

    const int m   = tid & 31;            // d row-pair index
    const int seg = tid >> 5;            // e 16-chunk index
    const int es  = seg << 4;            // e_local chunk start
    const int dg0 = d0 + 2 * m;          // global d of row 0 (row 1 = dg0+1)

    // classify this thread's 16-e chunk:
    // 0 = pure strict-lower (vector loads), 1 = straddles diagonal, 2 = zero
    int cls;
    if (dt >= 2 * ct + 2)      cls = 0;
    else if (dt == 2 * ct + 1) cls = (seg < 4) ? 0 : 1;
    else                       cls = (seg < 4) ? 1 : 2;

    const float* lowb = Llow + (size_t)kc * NLOW;
    const float2 wv = *(const float2*)(W + (size_t)kc * D_SZ + dg0);

    float v0[16], v1[16];
    if (cls == 0) {
        const int t0 = (dg0 * (dg0 - 1)) >> 1;       // tri(dg0)
        const int t1 = t0 + dg0;                     // tri(dg0+1)
        const float* s0 = lowb + t0 + e0 + es;
        const float* s1 = lowb + t1 + e0 + es;
        #pragma unroll
        for (int i = 0; i < 4; ++i) {
            f32x4u a = ((const f32x4u*)s0)[i];
            f32x4u b = ((const f32x4u*)s1)[i];
            #pragma unroll
            for (int j = 0; j < 4; ++j) { v0[i * 4 + j] = a[j]; v1[i * 4 + j] = b[j]; }
        }
    } else if (cls == 1) {
        const int t0 = (dg0 * (dg0 - 1)) >> 1;
        const int t1 = t0 + dg0;
        const float* diagb = Ldiag + (size_t)kc * D_SZ;
        float q0 = diagb[dg0],     q1 = diagb[dg0 + 1];
        q0 *= q0; q1 *= q1;
        #pragma unroll
        for (int j = 0; j < 16; ++j) {
            const int eg = e0 + es + j;
            v0[j] = (eg < dg0)     ? lowb[t0 + eg] : ((eg == dg0)     ? q0 : 0.f);
            v1[j] = (eg < dg0 + 1) ? lowb[t1 + eg] : ((eg == dg0 + 1) ? q1 : 0.f);
        }
    } else {
        #pragma unroll
        for (int j = 0; j < 16; ++j) { v0[j] = 0.f; v1[j] = 0.f; }
    }

    // transposed bf16 pair writes (conflict-free) + fp32 t-partials
    char* ltb = (char*)Lt;
    #pragma unroll
    for (int j = 0; j < 16; ++j) {
        const int el = es + j;
        union { __bf16 h[2]; unsigned u; } pk;
        pk.h[0] = (__bf16)v0[j];
        pk.h[1] = (__bf16)v1[j];
        const int off = el * 128 + ((4 * m) ^ ((el & 7) << 4));
        *(unsigned*)(ltb + off) = pk.u;
        ptl[m * 129 + el] = wv.x * v0[j] + wv.y * v1[j];
    }
    __syncthreads();

    // fragment-order page out: 4 lines/thread, one ds_read_b128 + 16B store.
    // zpage: lines >= 512 (e_local >= 64) are zero -> skip (never staged).
    __bf16* page = (__bf16*)Bp + (size_t)kc * CLASS_ELEMS + (size_t)s * STEP_ELEMS;
    const int lane = tid & 63, q = lane >> 4, c = lane & 15;
    #pragma unroll
    for (int k = 0; k < 4; ++k) {
        if (zpage && k >= 2) continue;
        const int ln = k * 256 + tid;
        const int up = ln >> 6;
        const int h  = up & 1;
        const int el = ((up >> 3) << 6) + (((up >> 1) & 3) << 4) + c;
        const int off = el * 128 + (((h << 6) + (q << 4)) ^ ((el & 7) << 4));
        *(bf16x8*)(page + (size_t)ln * 8) = *(const bf16x8*)(ltb + off);
    }

    // t-partial reduce over the 32 row-pairs
    if (tid < 128) {
        float sum = 0.f;
        #pragma unroll
        for (int mm = 0; mm < 32; ++mm) sum += ptl[mm * 129 + tid];
        tpart[((size_t)(kc * 8 + dt)) * 512 + e0 + tid] = sum;
    }
}

// ---------------------------------------------------------------------------
// K2: main GEMM (round-3 proven structure). A+B staged per step into LDS via
// global_load_lds, double-buffered, counted vmcnt (never 0 mid-loop), 2 raw
// barriers/step. t-reduce folded into the prologue (reads tpart directly).
// Zero-half steps (s in {0,8,14,18}): stage only 8 KB of B (vmcnt counts
// adjusted statically) and wng==1 waves skip frag-read+MFMA (contribution
// is exactly zero -> numerics identical).
// ---------------------------------------------------------------------------
__global__ __launch_bounds__(256, 2)
void gml2_main(const __hip_bfloat16* __restrict__ Xp,
               const __hip_bfloat16* __restrict__ Bp,
               const float* __restrict__ tpart,
               float* __restrict__ Out) {
    __shared__ __align__(16) char ldsbuf[2][32768];   // [buf][A 16K | B 16K]
    __shared__ float tvs[512];

    const int tid = threadIdx.x;
    const int bx  = blockIdx.x;
    // XCD swizzle: all 8 row-tiles of a class on one XCD -> pages L2-resident
    const int xcd = bx & 7;
    const int g   = bx >> 3;
    const int kc  = xcd * 32 + (g >> 3);
    const int mt  = g & 7;

    const int lane = tid & 63;
    const int wave = tid >> 6;
    const int wmg  = wave & 1;      // row 64-group
    const int wng  = wave >> 1;     // col 64-group
    const int c    = lane & 15;
    const int q    = lane >> 4;

    const __bf16* pA = (const __bf16*)Xp + (size_t)(mt * 8) * STEP_ELEMS;
    const __bf16* pB = (const __bf16*)Bp + (size_t)kc * CLASS_ELEMS;

    // LDS byte offsets of each fragment line (line*1024 + lane*16)
    int aoff[4][2], boff[4][2];
    #pragma unroll
    for (int mi = 0; mi < 4; ++mi)
        #pragma unroll
        for (int h = 0; h < 2; ++h)
            aoff[mi][h] = (((wmg * 4 + mi) * 2 + h) * 64 + lane) * 16;
    #pragma unroll
    for (int ni = 0; ni < 4; ++ni)
        #pragma unroll
        for (int h = 0; h < 2; ++h)
            boff[ni][h] = (((wng * 4 + ni) * 2 + h) * 64 + lane) * 16;

    f32x4 acc[4][4];
    #pragma unroll
    for (int mi = 0; mi < 4; ++mi)
        #pragma unroll
        for (int ni = 0; ni < 4; ++ni)
            acc[mi][ni] = (f32x4){0.f, 0.f, 0.f, 0.f};
    float rsum[16];
    #pragma unroll
    for (int i = 0; i < 16; ++i) rsum[i] = 0.f;

// stage step SIDX into buffer BUF: 4 A-chunks + NB B-chunks per wave
#define STAGE(BUF, SIDX, NB) {                                                 \
    const int kch_ = kch_of(SIDX);                                             \
    const char* ga_ = (const char*)(pA + (size_t)kch_ * STEP_ELEMS);           \
    const char* gb_ = (const char*)(pB + (size_t)(SIDX) * STEP_ELEMS);         \
    char* la_ = &ldsbuf[BUF][0];                                               \
    char* lb_ = &ldsbuf[BUF][16384];                                           \
    _Pragma("unroll") for (int i_ = 0; i_ < 4; ++i_) {                         \
        const int ch_ = (wave * 4 + i_) * 1024;                                \
        __builtin_amdgcn_global_load_lds(                                      \
            (const __attribute__((address_space(1))) void*)(ga_ + ch_ + lane * 16), \
            (__attribute__((address_space(3))) void*)(la_ + ch_), 16, 0, 0);   \
    }                                                                          \
    _Pragma("unroll") for (int i_ = 0; i_ < (NB); ++i_) {                      \
        const int ch_ = (wave * (NB) + i_) * 1024;                             \
        __builtin_amdgcn_global_load_lds(                                      \
            (const __attribute__((address_space(1))) void*)(gb_ + ch_ + lane * 16), \
            (__attribute__((address_space(3))) void*)(lb_ + ch_), 16, 0, 0);   \
    } }

#define WAIT8 asm volatile("s_waitcnt vmcnt(8)" ::: "memory")
#define WAIT6 asm volatile("s_waitcnt vmcnt(6)" ::: "memory")
#define WAIT0 asm volatile("s_waitcnt vmcnt(0)" ::: "memory")

// one K-step: literal S; ZS=1 if zero-half page; NBN = B-chunks of step S+1;
// WMAC = counted wait sized to step S+1's issue (4 + NBN)
#define GSTEP(S, ZS, NBN, WMAC) {                                              \
    if ((S) + 1 < NSTEPS) STAGE(((S) + 1) & 1, (S) + 1, NBN);                  \
    WMAC;                                                                      \
    __builtin_amdgcn_s_barrier();                                              \
    if (!(ZS) || wng == 0) {                                                   \
        const char* la_ = &ldsbuf[(S) & 1][0];                                 \
        const char* lb_ = &ldsbuf[(S) & 1][16384];                             \
        bf16x8 fa[4][2], fb[4][2];                                             \
        _Pragma("unroll") for (int mi = 0; mi < 4; ++mi)                       \
        _Pragma("unroll") for (int h = 0; h < 2; ++h)                          \
            fa[mi][h] = *(const bf16x8*)(la_ + aoff[mi][h]);                   \
        _Pragma("unroll") for (int ni = 0; ni < 4; ++ni)                       \
        _Pragma("unroll") for (int h = 0; h < 2; ++h)                          \
            fb[ni][h] = *(const bf16x8*)(lb_ + boff[ni][h]);                   \
        _Pragma("unroll") for (int h = 0; h < 2; ++h)                          \
        _Pragma("unroll") for (int mi = 0; mi < 4; ++mi)                       \
        _Pragma("unroll") for (int ni = 0; ni < 4; ++ni)                       \
            acc[mi][ni] = __builtin_amdgcn_mfma_f32_16x16x32_bf16(             \
                fa[mi][h], fb[ni][h], acc[mi][ni], 0, 0, 0);                   \
    }                                                                          \
    __builtin_amdgcn_s_barrier(); }

    // fold: subtract t and square-accumulate; C/D layout col=c(e), row=q*4+r(b)
#define FOLD(CT) {                                                             \
    float tv_[4];                                                              \
    _Pragma("unroll") for (int ni = 0; ni < 4; ++ni)                           \
        tv_[ni] = tvs[(CT) * 128 + wng * 64 + ni * 16 + c];                    \
    _Pragma("unroll") for (int mi = 0; mi < 4; ++mi)                           \
    _Pragma("unroll") for (int ni = 0; ni < 4; ++ni)                           \
    _Pragma("unroll") for (int r = 0; r < 4; ++r) {                            \
        float y_ = acc[mi][ni][r] - tv_[ni];                                   \
        rsum[mi * 4 + r] += y_ * y_;                                           \
        acc[mi][ni][r] = 0.f; } }

    STAGE(0, 0, 2);                      // s=0 is a zero-half page: 6 loads

    // t-reduce prologue: tvs[e] = sum over valid dt of tpart[kc][dt][e]
    // (same fp32 order as the old t_reduce kernel -> bitwise identical)
    if (tid < 128) {
        const int ctq = tid >> 5;        // ct of element 4*tid
        f32x4 ssum = (f32x4){0.f, 0.f, 0.f, 0.f};
        for (int dt = ctq << 1; dt < 8; ++dt)
            ssum += ((const f32x4*)(tpart + ((size_t)(kc * 8 + dt)) * 512))[tid];
        ((f32x4*)tvs)[tid] = ssum;
    }
    __syncthreads();   // publish tvs; also drains STAGE(0) (once, prologue only)

    GSTEP(0, 1, 4, WAIT8) GSTEP(1, 0, 4, WAIT8) GSTEP(2, 0, 4, WAIT8)
    GSTEP(3, 0, 4, WAIT8) GSTEP(4, 0, 4, WAIT8) GSTEP(5, 0, 4, WAIT8)
    GSTEP(6, 0, 4, WAIT8) GSTEP(7, 0, 2, WAIT6)
    FOLD(0)
    GSTEP(8, 1, 4, WAIT8) GSTEP(9, 0, 4, WAIT8) GSTEP(10, 0, 4, WAIT8)
    GSTEP(11, 0, 4, WAIT8) GSTEP(12, 0, 4, WAIT8) GSTEP(13, 0, 2, WAIT6)
    FOLD(1)
    GSTEP(14, 1, 4, WAIT8) GSTEP(15, 0, 4, WAIT8) GSTEP(16, 0, 4, WAIT8)
    GSTEP(17, 0, 2, WAIT6)
    FOLD(2)
    GSTEP(18, 1, 4, WAIT8) GSTEP(19, 0, 4, WAIT0)
    FOLD(3)

    // reduce the 16 e-lanes of each quad
    #pragma unroll
    for (int i = 0; i < 16; ++i) {
        float v = rsum[i];
        v += __shfl_xor(v, 1, 64);
        v += __shfl_xor(v, 2, 64);
        v += __shfl_xor(v, 4, 64);
        v += __shfl_xor(v, 8, 64);
        rsum[i] = v;
    }
    // osum aliases the staging LDS (all fragment reads done: last barrier above)
    float (*osum)[128] = (float(*)[128])&ldsbuf[0][0];
    if (c == 0) {
        #pragma unroll
        for (int mi = 0; mi < 4; ++mi)
            #pragma unroll
            for (int r = 0; r < 4; ++r)
                osum[wng][wmg * 64 + mi * 16 + q * 4 + r] = rsum[mi * 4 + r];
    }
    __syncthreads();
    if (tid < 128) {
        float v = osum[0][tid] + osum[1][tid];
        Out[(size_t)(mt * 128 + tid) * KC_SZ + kc] = sqrtf(v);
    }
}

// ---------------------------------------------------------------------------
// Fallback (round-2 kernel, proven, ws-independent).
// ---------------------------------------------------------------------------
#define FLDA 40
#define BM 128
#define BN 128
__device__ __forceinline__ void fstep_map(int s, int& ct, int& k0) {
    if (s < 16)      { ct = 0; k0 = s * 32; }
    else if (s < 28) { ct = 1; k0 = 128 + (s - 16) * 32; }
    else if (s < 36) { ct = 2; k0 = 256 + (s - 28) * 32; }
    else             { ct = 3; k0 = 384 + (s - 36) * 32; }
}
__global__ __launch_bounds__(256, 2)
void gml2_fallback(const float* __restrict__ X, const float* __restrict__ W,
                   const float* __restrict__ Ldiag, const float* __restrict__ Llow,
                   float* __restrict__ Out) {
    __shared__ __bf16 As[BM * FLDA];
    __shared__ __bf16 Bs[BN * FLDA];
    __shared__ float  Ws[D_SZ];
    __shared__ float  osum[2][BM];
    const int tid = threadIdx.x;
    const int bx  = blockIdx.x;
    const int xcd = bx & 7;
    const int g   = bx >> 3;
    const int kc  = xcd * 32 + (g >> 3);
    const int mt  = g & 7;
    const int lane = tid & 63, wave = tid >> 6;
    const int wm = (wave & 1) * 64, wn = (wave >> 1) * 64;
    const int c = lane & 15, q = lane >> 4;
    const int am = tid >> 1, akh = (tid & 1) << 4;
    const float* xrow = X + (size_t)(mt * BM + am) * D_SZ;
    const float* wrow = W + (size_t)kc * D_SZ;
    const int be = tid & 127, bd = (tid >> 7) << 4;
    const float* lowbase  = Llow  + (size_t)kc * NLOW;
    const float* diagbase = Ldiag + (size_t)kc * D_SZ;
    if (tid < 128) ((f32x4*)Ws)[tid] = ((const f32x4*)wrow)[tid];
    float rsum[16];
    #pragma unroll
    for (int i = 0; i < 16; ++i) rsum[i] = 0.f;
    f32x4 acc[4][4];
    #pragma unroll
    for (int mi = 0; mi < 4; ++mi)
        #pragma unroll
        for (int ni = 0; ni < 4; ++ni) acc[mi][ni] = (f32x4){0.f, 0.f, 0.f, 0.f};
    f32x4 xr[4];
    float bb[16];
    auto prefetch = [&](int s) {
        int pct, pk0; fstep_map(s, pct, pk0);
        const int pe0 = pct * BN;
        const float* xp = xrow + pk0 + akh;
        #pragma unroll
        for (int i = 0; i < 4; ++i) xr[i] = ((const f32x4*)xp)[i];
        const int e = pe0 + be, d0 = pk0 + bd;
        int tri = (d0 * (d0 - 1)) >> 1;
        if (pk0 >= pe0 + BN) {
            #pragma unroll
            for (int j = 0; j < 16; ++j) { bb[j] = lowbase[tri + e]; tri += d0 + j; }
        } else {
            #pragma unroll
            for (int j = 0; j < 16; ++j) {
                const int d = d0 + j;
                float val = 0.f;
                if (d > e)       val = lowbase[tri + e];
                else if (d == e) { float dq = diagbase[d]; val = dq * dq; }
                bb[j] = val; tri += d;
            }
        }
    };
    prefetch(0);
    __syncthreads();
    int cur_ct = 0;
    for (int s = 0; s < 40; ++s) {
        int ct, k0; fstep_map(s, ct, k0);
        if (ct != cur_ct) {
            #pragma unroll
            for (int mi = 0; mi < 4; ++mi)
                #pragma unroll
                for (int ni = 0; ni < 4; ++ni)
                    #pragma unroll
                    for (int r = 0; r < 4; ++r) {
                        float y = acc[mi][ni][r];
                        rsum[mi * 4 + r] += y * y;
                        acc[mi][ni][r] = 0.f;
                    }
            cur_ct = ct;
        }
        bf16x8 ap0, ap1;
        {
            const f32x4* wsp = (const f32x4*)&Ws[k0 + akh];
            #pragma unroll
            for (int i = 0; i < 4; ++i) {
                f32x4 wv = wsp[i];
                #pragma unroll
                for (int l = 0; l < 4; ++l) {
                    float v = xr[i][l] - wv[l];
                    int idx = i * 4 + l;
                    if (idx < 8) ap0[idx] = (__bf16)v;
                    else         ap1[idx - 8] = (__bf16)v;
                }
            }
        }
        bf16x8 bp0, bp1;
        #pragma unroll
        for (int j = 0; j < 8; ++j) { bp0[j] = (__bf16)bb[j]; bp1[j] = (__bf16)bb[j + 8]; }
        __syncthreads();
        *(bf16x8*)&As[am * FLDA + akh]     = ap0;
        *(bf16x8*)&As[am * FLDA + akh + 8] = ap1;
        *(bf16x8*)&Bs[be * FLDA + bd]      = bp0;
        *(bf16x8*)&Bs[be * FLDA + bd + 8]  = bp1;
        if (s + 1 < 40) prefetch(s + 1);
        __syncthreads();
        bf16x8 af[4], bfr[4];
        #pragma unroll
        for (int mi = 0; mi < 4; ++mi)
            af[mi] = *(const bf16x8*)&As[(wm + mi * 16 + c) * FLDA + q * 8];
        #pragma unroll
        for (int ni = 0; ni < 4; ++ni)
            bfr[ni] = *(const bf16x8*)&Bs[(wn + ni * 16 + c) * FLDA + q * 8];
        #pragma unroll
        for (int mi = 0; mi < 4; ++mi)
            #pragma unroll
            for (int ni = 0; ni < 4; ++ni)
                acc[mi][ni] = __builtin_amdgcn_mfma_f32_16x16x32_bf16(
                    af[mi], bfr[ni], acc[mi][ni], 0, 0, 0);
    }
    #pragma unroll
    for (int mi = 0; mi < 4; ++mi)
        #pragma unroll
        for (int ni = 0; ni < 4; ++ni)
            #pragma unroll
            for (int r = 0; r < 4; ++r) {
                float y = acc[mi][ni][r];
                rsum[mi * 4 + r] += y * y;
            }
    #pragma unroll
    for (int i = 0; i < 16; ++i) {
        float s = rsum[i];
        s += __shfl_xor(s, 1, 64);
        s += __shfl_xor(s, 2, 64);
        s += __shfl_xor(s, 4, 64);
        s += __shfl_xor(s, 8, 64);
        rsum[i] = s;
    }
    const int wnIdx = wave >> 1;
    if (c == 0) {
        #pragma unroll
        for (int mi = 0; mi < 4; ++mi)
            #pragma unroll
            for (int r = 0; r < 4; ++r)
                osum[wnIdx][wm + mi * 16 + q * 4 + r] = rsum[mi * 4 + r];
    }
    __syncthreads();
    if (tid < BM) {
        float s = osum[0][tid] + osum[1][tid];
        Out[(size_t)(mt * BM + tid) * KC_SZ + kc] = sqrtf(s);
    }
}

extern "C" void kernel_launch(void* const* d_in, const int* in_sizes, int n_in,
                              void* d_out, int out_size, void* d_ws, size_t ws_size,
                              hipStream_t stream) {
    const float* X  = (const float*)d_in[0];   // [1024, 512]
    const float* W  = (const float*)d_in[1];   // [256, 1, 512]
    const float* Ld = (const float*)d_in[2];   // [256, 512]
    const float* Ll = (const float*)d_in[3];   // [256, 130816]
    float* Out = (float*)d_out;                // [1024, 256]

    if (ws_size >= WS_NEED) {
        __hip_bfloat16* Bp    = (__hip_bfloat16*)d_ws;
        __hip_bfloat16* Xp    = (__hip_bfloat16*)((char*)d_ws + OFF_XP);
        float*          tpart = (float*)((char*)d_ws + OFF_TPART);
        prep_all<<<dim3(64 + NSTEPS * KC_SZ), dim3(256), 0, stream>>>(
            X, Ld, Ll, W, Xp, Bp, tpart);
        gml2_main<<<dim3(KC_SZ * 8), dim3(256), 0, stream>>>(Xp, Bp, tpart, Out);
    } else {
        gml2_fallback<<<dim3(KC_SZ * 8), dim3(256), 0, stream>>>(X, W, Ld, Ll, Out);
    }
}

// Round 7
// 307.212 us; speedup vs baseline: 1.9626x; 1.1297x over previous
//
#include <hip/hip_runtime.h>
#include <hip/hip_bf16.h>
#include <math.h>

// Problem constants
#define B_SZ   1024
#define D_SZ   512
#define KC_SZ  256
#define NLOW   130816            // 512*511/2

// B pages: per class, 20 K-step pages of 16 KB, stored in per-wave MFMA
// fragment order: line = ((wng*4+ni)*2+h)*64 + lane, lane = q*16+c,
// value[j] = L[d][e], e = wng*64+ni*16+c, d_local = h*32+q*8+j.
#define STEP_ELEMS  8192
#define NSTEPS      20           // 8+6+4+2 triangular K-steps
#define CLASS_ELEMS (NSTEPS * STEP_ELEMS)   // 320 KB/class

// Workspace layout (bytes)
#define OFF_XP     (size_t)(KC_SZ * CLASS_ELEMS * 2)        // 83886080
#define OFF_TPART  (OFF_XP + 64 * STEP_ELEMS * 2)           // +1 MiB
#define WS_NEED    (OFF_TPART + (size_t)KC_SZ * 8 * 512 * 4)

typedef __attribute__((ext_vector_type(4))) float  f32x4;
typedef __attribute__((ext_vector_type(4), aligned(4))) float f32x4u; // align-4 vector load
typedef __attribute__((ext_vector_type(8))) __bf16 bf16x8;

// steps before col-tile ct
__device__ __forceinline__ int sbase_of(int ct) { return ct * (9 - ct); }
// s -> dt (also the A-page k-chunk)
__device__ __forceinline__ int kch_of(int s) {
    return (s < 8) ? s : (s < 14) ? s - 6 : (s < 18) ? s - 10 : s - 12;
}

// ---------------------------------------------------------------------------
// K1: fused prep. Blocks [0,64): X pages (bf16, A-fragment order).
// Blocks [64, 64+20*256): B pages + t-partials (one block per class,page).
// Full 16 KB pages always written (zero halves come from the Lt tile, which
// holds zeros there) -- byte-identical to the proven round-3 prep_b output.
// ---------------------------------------------------------------------------
__global__ __launch_bounds__(256)
void prep_all(const float* __restrict__ X,
              const float* __restrict__ Ldiag,
              const float* __restrict__ Llow,
              const float* __restrict__ W,
              __hip_bfloat16* __restrict__ Xp,
              __hip_bfloat16* __restrict__ Bp,
              float* __restrict__ tpart) {
    __shared__ __bf16 Lt[128 * 64];      // [e_local][d_local], 16B-block XOR swizzle
    __shared__ float  ptl[32 * 129];     // [m][e_local], padded: bank=(m+e)%32

    const int bx  = blockIdx.x;
    const int tid = threadIdx.x;

    if (bx < 64) {
        // ---- prep_x: page pg = bx, 4 lines per thread ----
        const int pg  = bx;              // mt*8 + kch
        const int mt  = pg >> 3, kch = pg & 7;
        __bf16* out = (__bf16*)Xp + (size_t)pg * STEP_ELEMS;
        #pragma unroll
        for (int i = 0; i < 4; ++i) {
            const int line = tid + i * 256;          // 0..1023
            const int wmg = line >> 9, mi = (line >> 7) & 3, h = (line >> 6) & 1;
            const int lane = line & 63, q = lane >> 4, c = lane & 15;
            const int row = mt * 128 + wmg * 64 + mi * 16 + c;
            const float* src = X + (size_t)row * D_SZ + kch * 64 + h * 32 + q * 8;
            f32x4 v0 = ((const f32x4*)src)[0];
            f32x4 v1 = ((const f32x4*)src)[1];
            bf16x8 p;
            #pragma unroll
            for (int j = 0; j < 4; ++j) { p[j] = (__bf16)v0[j]; p[j + 4] = (__bf16)v1[j]; }
            *(bf16x8*)(out + line * 8) = p;
        }
        return;
    }

    // ---- prep_b: page s of class kc ----
    const int idx = bx - 64;
    const int s   = idx % 20;
    const int kc  = idx / 20;
    const int ct = (s < 8) ? 0 : (s < 14) ? 1 : (s < 18) ? 2 : 3;
    const int dt = kch_of(s);
    const int e0 = ct << 7, d0 = dt << 6;

    const int m   = tid & 31;            // d row-pair index
    const int seg = tid >> 5;            // e 16-chunk index
    const int es  = seg << 4;            // e_local chunk start
    const int dg0 = d0 + 2 * m;          // global d of row 0 (row 1 = dg0+1)

    // classify this thread's 16-e chunk:
    // 0 = pure strict-lower (vector loads), 1 = straddles diagonal, 2 = zero
    int cls;
    if (dt >= 2 * ct + 2)      cls = 0;
    else if (dt == 2 * ct + 1) cls = (seg < 4) ? 0 : 1;
    else                       cls = (seg < 4) ? 1 : 2;

    const float* lowb = Llow + (size_t)kc * NLOW;
    const float2 wv = *(const float2*)(W + (size_t)kc * D_SZ + dg0);

    float v0[16], v1[16];
    if (cls == 0) {
        const int t0 = (dg0 * (dg0 - 1)) >> 1;       // tri(dg0)
        const int t1 = t0 + dg0;                     // tri(dg0+1)
        const float* s0 = lowb + t0 + e0 + es;
        const float* s1 = lowb + t1 + e0 + es;
        #pragma unroll
        for (int i = 0; i < 4; ++i) {
            f32x4u a = ((const f32x4u*)s0)[i];
            f32x4u b = ((const f32x4u*)s1)[i];
            #pragma unroll
            for (int j = 0; j < 4; ++j) { v0[i * 4 + j] = a[j]; v1[i * 4 + j] = b[j]; }
        }
    } else if (cls == 1) {
        const int t0 = (dg0 * (dg0 - 1)) >> 1;
        const int t1 = t0 + dg0;
        const float* diagb = Ldiag + (size_t)kc * D_SZ;
        float q0 = diagb[dg0],     q1 = diagb[dg0 + 1];
        q0 *= q0; q1 *= q1;
        #pragma unroll
        for (int j = 0; j < 16; ++j) {
            const int eg = e0 + es + j;
            v0[j] = (eg < dg0)     ? lowb[t0 + eg] : ((eg == dg0)     ? q0 : 0.f);
            v1[j] = (eg < dg0 + 1) ? lowb[t1 + eg] : ((eg == dg0 + 1) ? q1 : 0.f);
        }
    } else {
        #pragma unroll
        for (int j = 0; j < 16; ++j) { v0[j] = 0.f; v1[j] = 0.f; }
    }

    // transposed bf16 pair writes (conflict-free) + fp32 t-partials
    char* ltb = (char*)Lt;
    #pragma unroll
    for (int j = 0; j < 16; ++j) {
        const int el = es + j;
        union { __bf16 h[2]; unsigned u; } pk;
        pk.h[0] = (__bf16)v0[j];
        pk.h[1] = (__bf16)v1[j];
        const int off = el * 128 + ((4 * m) ^ ((el & 7) << 4));
        *(unsigned*)(ltb + off) = pk.u;
        ptl[m * 129 + el] = wv.x * v0[j] + wv.y * v1[j];
    }
    __syncthreads();

    // fragment-order page out: 4 lines/thread, one ds_read_b128 + 16B store each
    __bf16* page = (__bf16*)Bp + (size_t)kc * CLASS_ELEMS + (size_t)s * STEP_ELEMS;
    const int lane = tid & 63, q = lane >> 4, c = lane & 15;
    #pragma unroll
    for (int k = 0; k < 4; ++k) {
        const int ln = k * 256 + tid;
        const int up = ln >> 6;
        const int h  = up & 1;
        const int el = ((up >> 3) << 6) + (((up >> 1) & 3) << 4) + c;
        const int off = el * 128 + (((h << 6) + (q << 4)) ^ ((el & 7) << 4));
        *(bf16x8*)(page + (size_t)ln * 8) = *(const bf16x8*)(ltb + off);
    }

    // t-partial reduce over the 32 row-pairs (tpart layout unchanged)
    if (tid < 128) {
        float sum = 0.f;
        #pragma unroll
        for (int mm = 0; mm < 32; ++mm) sum += ptl[mm * 129 + tid];
        tpart[((size_t)(kc * 8 + dt)) * 512 + e0 + tid] = sum;
    }
}

// ---------------------------------------------------------------------------
// K2: main GEMM -- EXACT round-3 K-loop structure (proven: 86 us, VGPR 116,
// zero spills). A+B staged per step into LDS via global_load_lds (uniform 8
// loads/wave), double-buffered, counted vmcnt(8) (never 0 mid-loop), 2 raw
// barriers/step, unconditional MFMA. Only additions vs round 3: the t-reduce
// fold (tvs prologue overlapped with STAGE(0), then copied once into the
// same 16 tvr registers round 3 used) -- saves the separate t_reduce launch.
// Round-6's conditional-MFMA zero-skip is REMOVED (it caused 151 MB of
// scratch spill traffic).
// ---------------------------------------------------------------------------
__global__ __launch_bounds__(256, 2)
void gml2_main(const __hip_bfloat16* __restrict__ Xp,
               const __hip_bfloat16* __restrict__ Bp,
               const float* __restrict__ tpart,
               float* __restrict__ Out) {
    // [buf][ A 16KB | B 16KB ] = 64 KB; osum aliased after last barrier
    __shared__ __align__(16) char ldsbuf[2][32768];
    __shared__ float tvs[512];

    const int tid = threadIdx.x;
    const int bx  = blockIdx.x;
    // XCD swizzle: all 8 row-tiles of a class on one XCD -> pages L2-resident
    const int xcd = bx & 7;
    const int g   = bx >> 3;
    const int kc  = xcd * 32 + (g >> 3);
    const int mt  = g & 7;

    const int lane = tid & 63;
    const int wave = tid >> 6;
    const int wmg  = wave & 1;      // row 64-group
    const int wng  = wave >> 1;     // col 64-group
    const int c    = lane & 15;
    const int q    = lane >> 4;

    const __bf16* pA = (const __bf16*)Xp + (size_t)(mt * 8) * STEP_ELEMS;
    const __bf16* pB = (const __bf16*)Bp + (size_t)kc * CLASS_ELEMS;

    // LDS byte offsets of each fragment line (line*1024 + lane*16)
    int aoff[4][2], boff[4][2];
    #pragma unroll
    for (int mi = 0; mi < 4; ++mi)
        #pragma unroll
        for (int h = 0; h < 2; ++h)
            aoff[mi][h] = (((wmg * 4 + mi) * 2 + h) * 64 + lane) * 16;
    #pragma unroll
    for (int ni = 0; ni < 4; ++ni)
        #pragma unroll
        for (int h = 0; h < 2; ++h)
            boff[ni][h] = (((wng * 4 + ni) * 2 + h) * 64 + lane) * 16;

    f32x4 acc[4][4];
    #pragma unroll
    for (int mi = 0; mi < 4; ++mi)
        #pragma unroll
        for (int ni = 0; ni < 4; ++ni)
            acc[mi][ni] = (f32x4){0.f, 0.f, 0.f, 0.f};
    float rsum[16];
    #pragma unroll
    for (int i = 0; i < 16; ++i) rsum[i] = 0.f;

    bf16x8 fa[4][2], fb[4][2];

// stage step SIDX into buffer BUF: 8 global_load_lds_dwordx4 per wave
// (4 A-chunks + 4 B-chunks of 1 KB, wave-uniform LDS dest + lane*16)
#define STAGE(BUF, SIDX) {                                                     \
    const int kch_ = kch_of(SIDX);                                             \
    const char* ga_ = (const char*)(pA + (size_t)kch_ * STEP_ELEMS);           \
    const char* gb_ = (const char*)(pB + (size_t)(SIDX) * STEP_ELEMS);         \
    char* la_ = &ldsbuf[BUF][0];                                               \
    char* lb_ = &ldsbuf[BUF][16384];                                           \
    _Pragma("unroll") for (int i_ = 0; i_ < 4; ++i_) {                         \
        const int ch_ = (wave * 4 + i_) * 1024;                                \
        __builtin_amdgcn_global_load_lds(                                      \
            (const __attribute__((address_space(1))) void*)(ga_ + ch_ + lane * 16), \
            (__attribute__((address_space(3))) void*)(la_ + ch_), 16, 0, 0);   \
        __builtin_amdgcn_global_load_lds(                                      \
            (const __attribute__((address_space(1))) void*)(gb_ + ch_ + lane * 16), \
            (__attribute__((address_space(3))) void*)(lb_ + ch_), 16, 0, 0);   \
    } }

#define LDS_FRAGS(BUF) {                                                       \
    const char* la_ = &ldsbuf[BUF][0];                                         \
    const char* lb_ = &ldsbuf[BUF][16384];                                     \
    _Pragma("unroll") for (int mi = 0; mi < 4; ++mi)                           \
    _Pragma("unroll") for (int h = 0; h < 2; ++h)                              \
        fa[mi][h] = *(const bf16x8*)(la_ + aoff[mi][h]);                       \
    _Pragma("unroll") for (int ni = 0; ni < 4; ++ni)                           \
    _Pragma("unroll") for (int h = 0; h < 2; ++h)                              \
        fb[ni][h] = *(const bf16x8*)(lb_ + boff[ni][h]); }

#define MFMA_ALL                                                               \
    _Pragma("unroll") for (int mi = 0; mi < 4; ++mi)                           \
    _Pragma("unroll") for (int ni = 0; ni < 4; ++ni)                           \
    _Pragma("unroll") for (int h = 0; h < 2; ++h)                              \
        acc[mi][ni] = __builtin_amdgcn_mfma_f32_16x16x32_bf16(                 \
            fa[mi][h], fb[ni][h], acc[mi][ni], 0, 0, 0);

    // fold: subtract t and square-accumulate; C/D layout col=c(e), row=q*4+r(b)
#define FOLD(CT) {                                                             \
    _Pragma("unroll") for (int mi = 0; mi < 4; ++mi)                           \
    _Pragma("unroll") for (int ni = 0; ni < 4; ++ni)                           \
    _Pragma("unroll") for (int r = 0; r < 4; ++r) {                            \
        float y_ = acc[mi][ni][r] - tvr[CT][ni];                               \
        rsum[mi * 4 + r] += y_ * y_;                                           \
        acc[mi][ni][r] = 0.f; } }

    STAGE(0, 0);

    // t-reduce prologue (overlaps STAGE(0) HBM latency):
    // tvs[e] = sum over valid dt of tpart[kc][dt][e] -- same fp32 order as
    // the old t_reduce kernel -> bitwise identical.
    if (tid < 128) {
        const int ctq = tid >> 5;        // ct of element 4*tid
        f32x4 ssum = (f32x4){0.f, 0.f, 0.f, 0.f};
        for (int dt = ctq << 1; dt < 8; ++dt)
            ssum += ((const f32x4*)(tpart + ((size_t)(kc * 8 + dt)) * 512))[tid];
        ((f32x4*)tvs)[tid] = ssum;
    }
    __syncthreads();                     // publish tvs (prologue only)

    // copy into the same 16 registers round 3 kept (FOLD is pure VALU)
    float tvr[4][4];
    #pragma unroll
    for (int ct4 = 0; ct4 < 4; ++ct4)
        #pragma unroll
        for (int ni = 0; ni < 4; ++ni)
            tvr[ct4][ni] = tvs[ct4 * 128 + wng * 64 + ni * 16 + c];

    #pragma unroll
    for (int s = 0; s < NSTEPS; ++s) {
        const int cur = s & 1;
        // fold boundaries (8, 14, 18): pure VALU, overlaps staging latency
        if (s == 8)       { FOLD(0); }
        else if (s == 14) { FOLD(1); }
        else if (s == 18) { FOLD(2); }

        if (s + 1 < NSTEPS) {
            STAGE(cur ^ 1, s + 1);
            // drain everything except the 8 just-issued next-stage loads
            asm volatile("s_waitcnt vmcnt(8)" ::: "memory");
        } else {
            asm volatile("s_waitcnt vmcnt(0)" ::: "memory");
        }
        __builtin_amdgcn_s_barrier();      // all waves: buf[cur] ready

        LDS_FRAGS(cur);                    // 16x ds_read_b128, conflict-free
        MFMA_ALL;                          // compiler inserts lgkm waits

        __builtin_amdgcn_s_barrier();      // all waves done reading buf[cur]
    }
    FOLD(3);

    // reduce the 16 e-lanes of each quad
    #pragma unroll
    for (int i = 0; i < 16; ++i) {
        float v = rsum[i];
        v += __shfl_xor(v, 1, 64);
        v += __shfl_xor(v, 2, 64);
        v += __shfl_xor(v, 4, 64);
        v += __shfl_xor(v, 8, 64);
        rsum[i] = v;
    }
    // osum aliases the staging LDS (all fragment reads done: last barrier above)
    float (*osum)[128] = (float(*)[128])&ldsbuf[0][0];
    if (c == 0) {
        #pragma unroll
        for (int mi = 0; mi < 4; ++mi)
            #pragma unroll
            for (int r = 0; r < 4; ++r)
                osum[wng][wmg * 64 + mi * 16 + q * 4 + r] = rsum[mi * 4 + r];
    }
    __syncthreads();
    if (tid < 128) {
        float v = osum[0][tid] + osum[1][tid];
        Out[(size_t)(mt * 128 + tid) * KC_SZ + kc] = sqrtf(v);
    }
}

// ---------------------------------------------------------------------------
// Fallback (round-2 kernel, proven, ws-independent).
// ---------------------------------------------------------------------------
#define FLDA 40
#define BM 128
#define BN 128
__device__ __forceinline__ void fstep_map(int s, int& ct, int& k0) {
    if (s < 16)      { ct = 0; k0 = s * 32; }
    else if (s < 28) { ct = 1; k0 = 128 + (s - 16) * 32; }
    else if (s < 36) { ct = 2; k0 = 256 + (s - 28) * 32; }
    else             { ct = 3; k0 = 384 + (s - 36) * 32; }
}
__global__ __launch_bounds__(256, 2)
void gml2_fallback(const float* __restrict__ X, const float* __restrict__ W,
                   const float* __restrict__ Ldiag, const float* __restrict__ Llow,
                   float* __restrict__ Out) {
    __shared__ __bf16 As[BM * FLDA];
    __shared__ __bf16 Bs[BN * FLDA];
    __shared__ float  Ws[D_SZ];
    __shared__ float  osum[2][BM];
    const int tid = threadIdx.x;
    const int bx  = blockIdx.x;
    const int xcd = bx & 7;
    const int g   = bx >> 3;
    const int kc  = xcd * 32 + (g >> 3);
    const int mt  = g & 7;
    const int lane = tid & 63, wave = tid >> 6;
    const int wm = (wave & 1) * 64, wn = (wave >> 1) * 64;
    const int c = lane & 15, q = lane >> 4;
    const int am = tid >> 1, akh = (tid & 1) << 4;
    const float* xrow = X + (size_t)(mt * BM + am) * D_SZ;
    const float* wrow = W + (size_t)kc * D_SZ;
    const int be = tid & 127, bd = (tid >> 7) << 4;
    const float* lowbase  = Llow  + (size_t)kc * NLOW;
    const float* diagbase = Ldiag + (size_t)kc * D_SZ;
    if (tid < 128) ((f32x4*)Ws)[tid] = ((const f32x4*)wrow)[tid];
    float rsum[16];
    #pragma unroll
    for (int i = 0; i < 16; ++i) rsum[i] = 0.f;
    f32x4 acc[4][4];
    #pragma unroll
    for (int mi = 0; mi < 4; ++mi)
        #pragma unroll
        for (int ni = 0; ni < 4; ++ni) acc[mi][ni] = (f32x4){0.f, 0.f, 0.f, 0.f};
    f32x4 xr[4];
    float bb[16];
    auto prefetch = [&](int s) {
        int pct, pk0; fstep_map(s, pct, pk0);
        const int pe0 = pct * BN;
        const float* xp = xrow + pk0 + akh;
        #pragma unroll
        for (int i = 0; i < 4; ++i) xr[i] = ((const f32x4*)xp)[i];
        const int e = pe0 + be, d0 = pk0 + bd;
        int tri = (d0 * (d0 - 1)) >> 1;
        if (pk0 >= pe0 + BN) {
            #pragma unroll
            for (int j = 0; j < 16; ++j) { bb[j] = lowbase[tri + e]; tri += d0 + j; }
        } else {
            #pragma unroll
            for (int j = 0; j < 16; ++j) {
                const int d = d0 + j;
                float val = 0.f;
                if (d > e)       val = lowbase[tri + e];
                else if (d == e) { float dq = diagbase[d]; val = dq * dq; }
                bb[j] = val; tri += d;
            }
        }
    };
    prefetch(0);
    __syncthreads();
    int cur_ct = 0;
    for (int s = 0; s < 40; ++s) {
        int ct, k0; fstep_map(s, ct, k0);
        if (ct != cur_ct) {
            #pragma unroll
            for (int mi = 0; mi < 4; ++mi)
                #pragma unroll
                for (int ni = 0; ni < 4; ++ni)
                    #pragma unroll
                    for (int r = 0; r < 4; ++r) {
                        float y = acc[mi][ni][r];
                        rsum[mi * 4 + r] += y * y;
                        acc[mi][ni][r] = 0.f;
                    }
            cur_ct = ct;
        }
        bf16x8 ap0, ap1;
        {
            const f32x4* wsp = (const f32x4*)&Ws[k0 + akh];
            #pragma unroll
            for (int i = 0; i < 4; ++i) {
                f32x4 wv = wsp[i];
                #pragma unroll
                for (int l = 0; l < 4; ++l) {
                    float v = xr[i][l] - wv[l];
                    int idx = i * 4 + l;
                    if (idx < 8) ap0[idx] = (__bf16)v;
                    else         ap1[idx - 8] = (__bf16)v;
                }
            }
        }
        bf16x8 bp0, bp1;
        #pragma unroll
        for (int j = 0; j < 8; ++j) { bp0[j] = (__bf16)bb[j]; bp1[j] = (__bf16)bb[j + 8]; }
        __syncthreads();
        *(bf16x8*)&As[am * FLDA + akh]     = ap0;
        *(bf16x8*)&As[am * FLDA + akh + 8] = ap1;
        *(bf16x8*)&Bs[be * FLDA + bd]      = bp0;
        *(bf16x8*)&Bs[be * FLDA + bd + 8]  = bp1;
        if (s + 1 < 40) prefetch(s + 1);
        __syncthreads();
        bf16x8 af[4], bfr[4];
        #pragma unroll
        for (int mi = 0; mi < 4; ++mi)
            af[mi] = *(const bf16x8*)&As[(wm + mi * 16 + c) * FLDA + q * 8];
        #pragma unroll
        for (int ni = 0; ni < 4; ++ni)
            bfr[ni] = *(const bf16x8*)&Bs[(wn + ni * 16 + c) * FLDA + q * 8];
        #pragma unroll
        for (int mi = 0; mi < 4; ++mi)
            #pragma unroll
            for (int ni = 0; ni < 4; ++ni)
                acc[mi][ni] = __builtin_amdgcn_mfma_f32_16x16x32_bf16(
                    af[mi], bfr[ni], acc[mi][ni], 0, 0, 0);
    }
    #pragma unroll
    for (int mi = 0; mi < 4; ++mi)
        #pragma unroll
        for (int ni = 0; ni < 4; ++ni)
            #pragma unroll
            for (int r = 0; r < 4; ++r) {
                float y = acc[mi][ni][r];
                rsum[mi * 4 + r] += y * y;
            }
    #pragma unroll
    for (int i = 0; i < 16; ++i) {
        float s = rsum[i];
        s += __shfl_xor(s, 1, 64);
        s += __shfl_xor(s, 2, 64);
        s += __shfl_xor(s, 4, 64);
        s += __shfl_xor(s, 8, 64);
        rsum[i] = s;
    }
    const int wnIdx = wave >> 1;
    if (c == 0) {
        #pragma unroll
        for (int mi = 0; mi < 4; ++mi)
            #pragma unroll
            for (int r = 0; r < 4; ++r)
                osum[wnIdx][wm + mi * 16 + q * 4 + r] = rsum[mi * 4 + r];
    }
    __syncthreads();
    if (tid < BM) {
        float s = osum[0][tid] + osum[1][tid];
        Out[(size_t)(mt * BM + tid) * KC_SZ + kc] = sqrtf(s);
    }
}

extern "C" void kernel_launch(void* const* d_in, const int* in_sizes, int n_in,
                              void* d_out, int out_size, void* d_ws, size_t ws_size,
                              hipStream_t stream) {
    const float* X  = (const float*)d_in[0];   // [1024, 512]
    const float* W  = (const float*)d_in[1];   // [256, 1, 512]
    const float* Ld = (const float*)d_in[2];   // [256, 512]
    const float* Ll = (const float*)d_in[3];   // [256, 130816]
    float* Out = (float*)d_out;                // [1024, 256]

    if (ws_size >= WS_NEED) {
        __hip_bfloat16* Bp    = (__hip_bfloat16*)d_ws;
        __hip_bfloat16* Xp    = (__hip_bfloat16*)((char*)d_ws + OFF_XP);
        float*          tpart = (float*)((char*)d_ws + OFF_TPART);
        prep_all<<<dim3(64 + NSTEPS * KC_SZ), dim3(256), 0, stream>>>(
            X, Ld, Ll, W, Xp, Bp, tpart);
        gml2_main<<<dim3(KC_SZ * 8), dim3(256), 0, stream>>>(Xp, Bp, tpart, Out);
    } else {
        gml2_fallback<<<dim3(KC_SZ * 8), dim3(256), 0, stream>>>(X, W, Ld, Ll, Out);
    }
}